// Round 14
// baseline (628.612 us; speedup 1.0000x reference)
//
#include <hip/hip_runtime.h>
#include <math.h>

#define NEG_SLOPE 0.2f
#define BN_EPS 1e-5f

template <int N> struct IC { static constexpr int v = N; };

typedef _Float16 half2v __attribute__((ext_vector_type(2)));
typedef _Float16 f16x8 __attribute__((ext_vector_type(8)));
typedef float f32x4v __attribute__((ext_vector_type(4)));

__device__ __forceinline__ half2v u2h(unsigned u) {
  union { unsigned u; half2v h; } c;
  c.u = u;
  return c.h;
}
__device__ __forceinline__ unsigned pkh(float lo, float hi) {
  union { half2v h; unsigned u; } c;
  c.h[0] = (_Float16)lo;
  c.h[1] = (_Float16)hi;
  return c.u;
}

#if defined(__has_builtin)
#if __has_builtin(__builtin_amdgcn_fdot2)
#define FDOT2(a, b, c) __builtin_amdgcn_fdot2((a), (b), (c), false)
#endif
#endif
#ifndef FDOT2
__device__ __forceinline__ float fdot2_sw(half2v a, half2v b, float c) {
  return c + (float)a[0] * (float)b[0] + (float)a[1] * (float)b[1];
}
#define FDOT2(a, b, c) fdot2_sw((a), (b), (c))
#endif

// Fast exp: raw v_exp_f32 (2^x) with att pre-scaled by log2(e).
#if defined(__has_builtin)
#if __has_builtin(__builtin_amdgcn_exp2f)
#define FEXP(x) __builtin_amdgcn_exp2f(x)
#define ATT_SCALE 1.44269504088896f
#endif
#endif
#ifndef FEXP
#define FEXP(x) __expf(x)
#define ATT_SCALE 1.0f
#endif

// FMA of one float4 pair into scalar accumulator (expanded inline at use).
#define FMA4(acc, v, wq) \
  acc += (v).x * (wq).x + (v).y * (wq).y + (v).z * (wq).z + (v).w * (wq).w

// One 64-dot row-pass against register-resident W[16] (float4).
// sched_barrier(0) fences the scheduler (round-4 proven; no spills).
#define DOT_ROW(buf, stride, r, bias, OUT)                                  \
  {                                                                         \
    __builtin_amdgcn_sched_barrier(0);                                      \
    float a0 = 0.f, a1 = 0.f, a2 = 0.f, a3 = 0.f;                           \
    _Pragma("unroll") for (int q = 0; q < 4; q++) {                         \
      float4 v0 = *(const float4*)((buf) + (r) * (stride) + q * 16 + 0);    \
      float4 v1 = *(const float4*)((buf) + (r) * (stride) + q * 16 + 4);    \
      float4 v2 = *(const float4*)((buf) + (r) * (stride) + q * 16 + 8);    \
      float4 v3 = *(const float4*)((buf) + (r) * (stride) + q * 16 + 12);   \
      FMA4(a0, v0, W[q * 4 + 0]);                                           \
      FMA4(a1, v1, W[q * 4 + 1]);                                           \
      FMA4(a2, v2, W[q * 4 + 2]);                                           \
      FMA4(a3, v3, W[q * 4 + 3]);                                           \
    }                                                                       \
    OUT = (bias) + ((a0 + a1) + (a2 + a3));                                 \
  }

// ---------------------------------------------------------------------------
// 16-lane row sum via DPP rotation-reduce: after adding rotations by 1,2,4,8
// every lane in the 16-lane row holds the full row sum. 8 VALU, no broadcast.
// ---------------------------------------------------------------------------
__device__ __forceinline__ float row_sum16(float v) {
  int x;
  x = __builtin_amdgcn_update_dpp(0, __float_as_int(v), 0x121, 0xF, 0xF, true);
  v += __int_as_float(x);  // row_ror:1
  x = __builtin_amdgcn_update_dpp(0, __float_as_int(v), 0x122, 0xF, 0xF, true);
  v += __int_as_float(x);  // row_ror:2
  x = __builtin_amdgcn_update_dpp(0, __float_as_int(v), 0x124, 0xF, 0xF, true);
  v += __int_as_float(x);  // row_ror:4
  x = __builtin_amdgcn_update_dpp(0, __float_as_int(v), 0x128, 0xF, 0xF, true);
  v += __int_as_float(x);  // row_ror:8 -> every lane = row total
  return v;
}

#if defined(__has_builtin)
#if __has_builtin(__builtin_amdgcn_mfma_f32_16x16x32_f16)
#define HAVE_MFMA16 1
#endif
#endif

// ---------------------------------------------------------------------------
// hist + graph-counts + fp16 weight pack (Wl,Wr,We — all independent).
// ---------------------------------------------------------------------------
__global__ __launch_bounds__(256) void hist_kernel(
    const int* __restrict__ dst, const int* __restrict__ batch,
    int* __restrict__ deg, float* __restrict__ counts,
    const float* __restrict__ Wl, const float* __restrict__ Wr,
    const float* __restrict__ We, _Float16* __restrict__ w16, int E_,
    int N_) {
  int i = blockIdx.x * 256 + threadIdx.x;
  if (i < E_) atomicAdd(&deg[dst[i]], 1);
  if (i < N_) atomicAdd(&counts[batch[i]], 1.0f);
  if (i < 12288) {
    w16[i] = (_Float16)Wl[i];
  } else if (i < 24576) {
    w16[i] = (_Float16)Wr[i - 12288];
  } else if (i < 27648) {
    w16[i] = (_Float16)We[i - 24576];
  }
}

// ---------------------------------------------------------------------------
// scanA: per-256-segment local prefix + totals; FUSED degree histogram
// (128 bins, DESCENDING degree, LDS-aggregated).
// ---------------------------------------------------------------------------
__global__ __launch_bounds__(256) void scanA_kernel(
    const int* __restrict__ deg, int* __restrict__ row_ptr,
    int* __restrict__ segTot, int* __restrict__ bins, int N_, int nseg) {
  __shared__ int sb[256];
  __shared__ int lb[128];
  int t = threadIdx.x;
  if (t < 128) lb[t] = 0;
  __syncthreads();
  for (int s = blockIdx.x; s < nseg; s += gridDim.x) {
    int i = s * 256 + t;
    int v = (i < N_) ? deg[i] : 0;
    if (i < N_) atomicAdd(&lb[127 - min(v, 127)], 1);
    sb[t] = v;
    __syncthreads();
    for (int off = 1; off < 256; off <<= 1) {
      int a = (t >= off) ? sb[t - off] : 0;
      __syncthreads();
      sb[t] += a;
      __syncthreads();
    }
    int incl = sb[t];
    if (i < N_) row_ptr[i] = incl - v;
    if (t == 255) segTot[s] = incl;
    __syncthreads();
  }
  if (t < 128 && lb[t]) atomicAdd(&bins[t], lb[t]);
}

// ---------------------------------------------------------------------------
// scanB: scan segTot; FUSED exclusive scan of the 128 degree bins.
// ---------------------------------------------------------------------------
__global__ __launch_bounds__(256) void scanB_kernel(int* __restrict__ segTot,
                                                    int* __restrict__ bins,
                                                    int nseg) {
  __shared__ int sb[256];
  __shared__ int baseSh;
  int t = threadIdx.x;
  if (t == 0) baseSh = 0;
  __syncthreads();
  for (int c0 = 0; c0 < nseg; c0 += 256) {
    int s = c0 + t;
    int v = (s < nseg) ? segTot[s] : 0;
    sb[t] = v;
    __syncthreads();
    for (int off = 1; off < 256; off <<= 1) {
      int a = (t >= off) ? sb[t - off] : 0;
      __syncthreads();
      sb[t] += a;
      __syncthreads();
    }
    int incl = sb[t];
    int base = baseSh;
    if (s < nseg) segTot[s] = base + incl - v;
    __syncthreads();
    if (t == 255) baseSh = base + incl;
    __syncthreads();
  }
  int v2 = (t < 128) ? bins[t] : 0;
  sb[t] = v2;
  __syncthreads();
  for (int off = 1; off < 256; off <<= 1) {
    int a = (t >= off) ? sb[t - off] : 0;
    __syncthreads();
    sb[t] += a;
    __syncthreads();
  }
  if (t < 128) bins[t] = sb[t] - v2;
}

// ---------------------------------------------------------------------------
// scanC: finalize row_ptr/cursor; FUSED degree-sort scatter; zero csr pads.
// ---------------------------------------------------------------------------
__global__ __launch_bounds__(256) void scanC_kernel(
    int* __restrict__ row_ptr, const int* __restrict__ segTot,
    int* __restrict__ cursor, const int* __restrict__ deg,
    int* __restrict__ bins, int* __restrict__ perm,
    int* __restrict__ csr_src, int* __restrict__ csr_eid, int N_, int E_) {
  __shared__ int lb[128];
  __shared__ int lbase[128];
  int t = threadIdx.x;
  if (t < 128) lb[t] = 0;
  __syncthreads();
  int i = blockIdx.x * 256 + t;
  int bin = 0, rk = 0;
  bool ok = (i < N_);
  if (ok) {
    int rp = row_ptr[i] + segTot[i >> 8];
    row_ptr[i] = rp;
    cursor[i] = rp;
    int dg = deg[i];
    bin = 127 - min(dg, 127);
    rk = atomicAdd(&lb[bin], 1);
  }
  if (i == 0) row_ptr[N_] = E_;
  if (blockIdx.x == 0 && t < 16) {
    csr_src[E_ + t] = 0;
    csr_eid[E_ + t] = 0;
  }
  __syncthreads();
  if (t < 128) {
    int c = lb[t];
    lbase[t] = c ? atomicAdd(&bins[t], c) : 0;
  }
  __syncthreads();
  if (ok) perm[lbase[bin] + rk] = i;
}

// ---------------------------------------------------------------------------
// Scatter: 4B-only random writes (L2-resident).
// ---------------------------------------------------------------------------
__global__ __launch_bounds__(256) void scatter_kernel(
    const int* __restrict__ src, const int* __restrict__ dst,
    int* __restrict__ cursor, int* __restrict__ csr_src,
    int* __restrict__ csr_eid, int E_) {
  int e = blockIdx.x * 256 + threadIdx.x;
  if (e >= E_) return;
  int pos = atomicAdd(&cursor[dst[e]], 1);
  csr_src[pos] = src[e];
  csr_eid[pos] = e;
}

// ---------------------------------------------------------------------------
// Permute+convert attr: sequential coalesced 32B writes; random 64B-line
// gathers (each line read exactly once).
// ---------------------------------------------------------------------------
__global__ __launch_bounds__(256) void permute_attr_kernel(
    const float4* __restrict__ edge_attr4, const int* __restrict__ csr_eid,
    unsigned* __restrict__ attr_u, int E_) {
  int p = blockIdx.x * 256 + threadIdx.x;
  if (p >= E_) return;
  int e = csr_eid[p];
  float4 a0 = edge_attr4[(size_t)e * 4 + 0];
  float4 a1 = edge_attr4[(size_t)e * 4 + 1];
  float4 a2 = edge_attr4[(size_t)e * 4 + 2];
  float4 a3 = edge_attr4[(size_t)e * 4 + 3];
  uint4 u0, u1;
  u0.x = pkh(a0.x, a0.y);
  u0.y = pkh(a0.z, a0.w);
  u0.z = pkh(a1.x, a1.y);
  u0.w = pkh(a1.z, a1.w);
  u1.x = pkh(a2.x, a2.y);
  u1.y = pkh(a2.z, a2.w);
  u1.z = pkh(a3.x, a3.y);
  u1.w = pkh(a3.z, a3.w);
  uint4* d4 = (uint4*)(attr_u + (size_t)p * 8);
  d4[0] = u0;
  d4[1] = u1;
}

// ---------------------------------------------------------------------------
// emb + FUSED layer-0 linx (round-11 proven).
// ---------------------------------------------------------------------------
__global__ __launch_bounds__(256, 3) void emb_kernel(
    const float* __restrict__ x, const float* __restrict__ emb_W,
    const float* __restrict__ emb_b, const _Float16* __restrict__ Wl16,
    const float* __restrict__ bl, const _Float16* __restrict__ Wr16,
    const float* __restrict__ br, float* __restrict__ h,
    _Float16* __restrict__ xl, _Float16* __restrict__ xr, int rows) {
  __shared__ float sx[4096];
  __shared__ float sh[64 * 68];
  int lane = threadIdx.x & 63;
  int w = threadIdx.x >> 6;
  int n0 = blockIdx.x * 64;

  {
    int gmax = rows * 64 - 4;
#pragma unroll
    for (int i = 0; i < 4; i++) {
      int off = w * 1024 + i * 256 + lane * 4;
      int g = min(n0 * 64 + off, gmax);
      *(float4*)(sx + off) = *(const float4*)(x + g);
    }
  }

  {
    float4 W[16];
#pragma unroll
    for (int q = 0; q < 16; q++) W[q] = ((const float4*)(emb_W + lane * 64))[q];
    float b = emb_b[lane];
#pragma unroll 1
    for (int t = 0; t < 16; t++) {
      int r = w * 16 + t;
      float a;
      DOT_ROW(sx, 64, r, b, a);
      sh[r * 68 + lane] = a;
      int n = n0 + r;
      if (n < rows) h[(size_t)n * 64 + lane] = a;
    }
  }

#ifdef HAVE_MFMA16
  {
    int r = lane & 15;
    int kg = lane >> 4;
    int nb = n0 + w * 16;
    const float* p = sh + (w * 16 + r) * 68 + kg * 8;
    f16x8 A0, A1;
    {
      float4 xa = *(const float4*)(p);
      float4 xb = *(const float4*)(p + 4);
      A0[0] = (_Float16)xa.x; A0[1] = (_Float16)xa.y;
      A0[2] = (_Float16)xa.z; A0[3] = (_Float16)xa.w;
      A0[4] = (_Float16)xb.x; A0[5] = (_Float16)xb.y;
      A0[6] = (_Float16)xb.z; A0[7] = (_Float16)xb.w;
      xa = *(const float4*)(p + 32);
      xb = *(const float4*)(p + 36);
      A1[0] = (_Float16)xa.x; A1[1] = (_Float16)xa.y;
      A1[2] = (_Float16)xa.z; A1[3] = (_Float16)xa.w;
      A1[4] = (_Float16)xb.x; A1[5] = (_Float16)xb.y;
      A1[6] = (_Float16)xb.z; A1[7] = (_Float16)xb.w;
    }
#pragma unroll
    for (int c = 0; c < 4; c++) {
      int o = c * 16 + r;
      {
        const f16x8* b0 = (const f16x8*)(Wl16 + (size_t)o * 64 + kg * 8);
        const f16x8* b1 = (const f16x8*)(Wl16 + (size_t)o * 64 + 32 + kg * 8);
        f32x4v acc;
        float bv = bl[o];
        acc[0] = bv; acc[1] = bv; acc[2] = bv; acc[3] = bv;
        acc = __builtin_amdgcn_mfma_f32_16x16x32_f16(A0, b0[0], acc, 0, 0, 0);
        acc = __builtin_amdgcn_mfma_f32_16x16x32_f16(A1, b1[0], acc, 0, 0, 0);
#pragma unroll
        for (int g = 0; g < 4; g++) {
          int nd = nb + kg * 4 + g;
          if (nd < rows) xl[(size_t)nd * 64 + o] = (_Float16)acc[g];
        }
      }
      {
        const f16x8* b0 = (const f16x8*)(Wr16 + (size_t)o * 64 + kg * 8);
        const f16x8* b1 = (const f16x8*)(Wr16 + (size_t)o * 64 + 32 + kg * 8);
        f32x4v acc;
        float bv = br[o];
        acc[0] = bv; acc[1] = bv; acc[2] = bv; acc[3] = bv;
        acc = __builtin_amdgcn_mfma_f32_16x16x32_f16(A0, b0[0], acc, 0, 0, 0);
        acc = __builtin_amdgcn_mfma_f32_16x16x32_f16(A1, b1[0], acc, 0, 0, 0);
#pragma unroll
        for (int g = 0; g < 4; g++) {
          int nd = nb + kg * 4 + g;
          if (nd < rows) xr[(size_t)nd * 64 + o] = (_Float16)acc[g];
        }
      }
    }
  }
#endif
}

// ---------------------------------------------------------------------------
// linx via MFMA (round-8 proven). Layers 1,2.
// ---------------------------------------------------------------------------
__global__ __launch_bounds__(256) void linx_mfma_kernel(
    const float* __restrict__ in, const _Float16* __restrict__ Wl16,
    const float* __restrict__ bl, const _Float16* __restrict__ Wr16,
    const float* __restrict__ br, _Float16* __restrict__ xl,
    _Float16* __restrict__ xr, int rows) {
#ifdef HAVE_MFMA16
  int lane = threadIdx.x & 63;
  int w = threadIdx.x >> 6;
  int n0 = blockIdx.x * 64 + w * 16;
  int r = lane & 15;
  int kg = lane >> 4;

  int nA = min(n0 + r, rows - 1);
  f16x8 A0, A1;
  {
    const float* p = in + (size_t)nA * 64 + kg * 8;
    float4 xa = *(const float4*)(p);
    float4 xb = *(const float4*)(p + 4);
    A0[0] = (_Float16)xa.x; A0[1] = (_Float16)xa.y;
    A0[2] = (_Float16)xa.z; A0[3] = (_Float16)xa.w;
    A0[4] = (_Float16)xb.x; A0[5] = (_Float16)xb.y;
    A0[6] = (_Float16)xb.z; A0[7] = (_Float16)xb.w;
    xa = *(const float4*)(p + 32);
    xb = *(const float4*)(p + 36);
    A1[0] = (_Float16)xa.x; A1[1] = (_Float16)xa.y;
    A1[2] = (_Float16)xa.z; A1[3] = (_Float16)xa.w;
    A1[4] = (_Float16)xb.x; A1[5] = (_Float16)xb.y;
    A1[6] = (_Float16)xb.z; A1[7] = (_Float16)xb.w;
  }

#pragma unroll
  for (int c = 0; c < 4; c++) {
    int o = c * 16 + r;
    {
      const f16x8* b0 = (const f16x8*)(Wl16 + (size_t)o * 64 + kg * 8);
      const f16x8* b1 = (const f16x8*)(Wl16 + (size_t)o * 64 + 32 + kg * 8);
      f32x4v acc;
      float bv = bl[o];
      acc[0] = bv; acc[1] = bv; acc[2] = bv; acc[3] = bv;
      acc = __builtin_amdgcn_mfma_f32_16x16x32_f16(A0, b0[0], acc, 0, 0, 0);
      acc = __builtin_amdgcn_mfma_f32_16x16x32_f16(A1, b1[0], acc, 0, 0, 0);
#pragma unroll
      for (int g = 0; g < 4; g++) {
        int nd = n0 + kg * 4 + g;
        if (nd < rows) xl[(size_t)nd * 64 + o] = (_Float16)acc[g];
      }
    }
    {
      const f16x8* b0 = (const f16x8*)(Wr16 + (size_t)o * 64 + kg * 8);
      const f16x8* b1 = (const f16x8*)(Wr16 + (size_t)o * 64 + 32 + kg * 8);
      f32x4v acc;
      float bv = br[o];
      acc[0] = bv; acc[1] = bv; acc[2] = bv; acc[3] = bv;
      acc = __builtin_amdgcn_mfma_f32_16x16x32_f16(A0, b0[0], acc, 0, 0, 0);
      acc = __builtin_amdgcn_mfma_f32_16x16x32_f16(A1, b1[0], acc, 0, 0, 0);
#pragma unroll
      for (int g = 0; g < 4; g++) {
        int nd = n0 + kg * 4 + g;
        if (nd < rows) xr[(size_t)nd * 64 + o] = (_Float16)acc[g];
      }
    }
  }
#endif
}

// ---------------------------------------------------------------------------
// Fused GATv2 layer, 4 edges per wave-step WITHIN one node per wave:
// lane = (eg = lane>>4 edge subgroup, jj = lane&15 dim group, 4 dims/lane).
// Edges are CSR-contiguous -> si/xl/attr loads coalesced or group-broadcast.
// 16-lane DPP rotation-reduce (8 VALU / 4 edges); cross-group max via 2
// shfl_xor once per chunk; online softmax in exp2 domain. Epilogue: combine
// l/acc across groups (butterfly), folded BN, exact GELU, residual (eg==0
// lanes write float4).
// ---------------------------------------------------------------------------
template <bool CONTIG>
__global__ __launch_bounds__(256) void gat_fused_kernel(
    const int* __restrict__ perm, const int* __restrict__ csr_src,
    const int* __restrict__ csr_eid, const int* __restrict__ row_ptr,
    const unsigned* __restrict__ attr_u, const float* __restrict__ edge_attr,
    const _Float16* __restrict__ xl, const _Float16* __restrict__ xr,
    const _Float16* __restrict__ we16, const float* __restrict__ We,
    const float* __restrict__ att, const float* __restrict__ conv_bias,
    const float* __restrict__ gamma, const float* __restrict__ beta,
    const float* __restrict__ mean, const float* __restrict__ var,
    float* __restrict__ h, int N_) {
  int widx = (blockIdx.x * 256 + threadIdx.x) >> 6;
  if (widx >= N_) return;
  int d = __builtin_amdgcn_readfirstlane(perm[widx]);
  int lane = threadIdx.x & 63;
  int jj = lane & 15;  // dim group: dims 4jj..4jj+3
  int eg = lane >> 4;  // edge subgroup 0..3

  // We rows for my 4 dims (fp16 pairs for fdot2).
  half2v Wk[4][8];
  float Wf[4][16];
  if constexpr (CONTIG) {
    const uint4* wp = (const uint4*)(we16 + jj * 64);  // 4 rows x 16 fp16
#pragma unroll
    for (int i = 0; i < 4; i++) {
      uint4 wa = wp[2 * i], wb = wp[2 * i + 1];
      Wk[i][0] = u2h(wa.x);
      Wk[i][1] = u2h(wa.y);
      Wk[i][2] = u2h(wa.z);
      Wk[i][3] = u2h(wa.w);
      Wk[i][4] = u2h(wb.x);
      Wk[i][5] = u2h(wb.y);
      Wk[i][6] = u2h(wb.z);
      Wk[i][7] = u2h(wb.w);
    }
  } else {
#pragma unroll
    for (int i = 0; i < 4; i++)
#pragma unroll
      for (int k = 0; k < 16; k++) Wf[i][k] = We[(4 * jj + i) * 16 + k];
  }
  float4 attv = *(const float4*)(att + jj * 4);
  float at0 = attv.x * ATT_SCALE, at1 = attv.y * ATT_SCALE;
  float at2 = attv.z * ATT_SCALE, at3 = attv.w * ATT_SCALE;
  float4 varv = *(const float4*)(var + jj * 4);
  float4 gamv = *(const float4*)(gamma + jj * 4);
  float4 cbv = *(const float4*)(conv_bias + jj * 4);
  float4 mev = *(const float4*)(mean + jj * 4);
  float4 bev = *(const float4*)(beta + jj * 4);
  float sc0 = rsqrtf(varv.x + BN_EPS) * gamv.x;
  float sh0 = (cbv.x - mev.x) * sc0 + bev.x;
  float sc1 = rsqrtf(varv.y + BN_EPS) * gamv.y;
  float sh1 = (cbv.y - mev.y) * sc1 + bev.y;
  float sc2 = rsqrtf(varv.z + BN_EPS) * gamv.z;
  float sh2 = (cbv.z - mev.z) * sc2 + bev.z;
  float sc3 = rsqrtf(varv.w + BN_EPS) * gamv.w;
  float sh3 = (cbv.w - mev.w) * sc3 + bev.w;

  int beg = __builtin_amdgcn_readfirstlane(row_ptr[d]);
  int end = __builtin_amdgcn_readfirstlane(row_ptr[d + 1]);
  int deg = end - beg;
  int degm1 = max(deg - 1, 0);

  float xr0, xr1, xr2, xr3;
  {
    uint2 xp = *(const uint2*)((const char*)xr + (size_t)d * 128 + jj * 8);
    half2v h0 = u2h(xp.x), h1 = u2h(xp.y);
    xr0 = (float)h0[0];
    xr1 = (float)h0[1];
    xr2 = (float)h1[0];
    xr3 = (float)h1[1];
  }

  float m = -INFINITY, l = 0.f;
  float a0 = 0.f, a1 = 0.f, a2 = 0.f, a3 = 0.f;

  auto chunk = [&](int base, auto C_) {
    constexpr int C = decltype(C_)::v;  // steps of 4 edges
    int idxv[C];
    bool msk[C];
#pragma unroll
    for (int k = 0; k < C; k++) {
      int t = base + k * 4 + eg;
      idxv[k] = beg + min(t, degm1);
      msk[k] = t < deg;
    }
    int si[C];
#pragma unroll
    for (int k = 0; k < C; k++) si[k] = csr_src[idxv[k]];
    uint2 xpk[C];
#pragma unroll
    for (int k = 0; k < C; k++)
      xpk[k] = *(const uint2*)((const char*)xl + (size_t)si[k] * 128 + jj * 8);
    float v[C];
#pragma unroll
    for (int k = 0; k < C; k++) {
      float ea0, ea1, ea2, ea3;
      if constexpr (CONTIG) {
        const uint4* ap = (const uint4*)(attr_u + (size_t)idxv[k] * 8);
        uint4 ua = ap[0], ub = ap[1];  // 16-lane group broadcast
        ea0 = 0.f; ea1 = 0.f; ea2 = 0.f; ea3 = 0.f;
        half2v c0 = u2h(ua.x), c1 = u2h(ua.y), c2 = u2h(ua.z), c3 = u2h(ua.w);
        half2v c4 = u2h(ub.x), c5 = u2h(ub.y), c6 = u2h(ub.z), c7 = u2h(ub.w);
        ea0 = FDOT2(c0, Wk[0][0], ea0); ea0 = FDOT2(c1, Wk[0][1], ea0);
        ea0 = FDOT2(c2, Wk[0][2], ea0); ea0 = FDOT2(c3, Wk[0][3], ea0);
        ea0 = FDOT2(c4, Wk[0][4], ea0); ea0 = FDOT2(c5, Wk[0][5], ea0);
        ea0 = FDOT2(c6, Wk[0][6], ea0); ea0 = FDOT2(c7, Wk[0][7], ea0);
        ea1 = FDOT2(c0, Wk[1][0], ea1); ea1 = FDOT2(c1, Wk[1][1], ea1);
        ea1 = FDOT2(c2, Wk[1][2], ea1); ea1 = FDOT2(c3, Wk[1][3], ea1);
        ea1 = FDOT2(c4, Wk[1][4], ea1); ea1 = FDOT2(c5, Wk[1][5], ea1);
        ea1 = FDOT2(c6, Wk[1][6], ea1); ea1 = FDOT2(c7, Wk[1][7], ea1);
        ea2 = FDOT2(c0, Wk[2][0], ea2); ea2 = FDOT2(c1, Wk[2][1], ea2);
        ea2 = FDOT2(c2, Wk[2][2], ea2); ea2 = FDOT2(c3, Wk[2][3], ea2);
        ea2 = FDOT2(c4, Wk[2][4], ea2); ea2 = FDOT2(c5, Wk[2][5], ea2);
        ea2 = FDOT2(c6, Wk[2][6], ea2); ea2 = FDOT2(c7, Wk[2][7], ea2);
        ea3 = FDOT2(c0, Wk[3][0], ea3); ea3 = FDOT2(c1, Wk[3][1], ea3);
        ea3 = FDOT2(c2, Wk[3][2], ea3); ea3 = FDOT2(c3, Wk[3][3], ea3);
        ea3 = FDOT2(c4, Wk[3][4], ea3); ea3 = FDOT2(c5, Wk[3][5], ea3);
        ea3 = FDOT2(c6, Wk[3][6], ea3); ea3 = FDOT2(c7, Wk[3][7], ea3);
      } else {
        int e = csr_eid[idxv[k]];
        const float4* ap = (const float4*)(edge_attr + (size_t)e * 16);
        float4 q0 = ap[0], q1 = ap[1], q2 = ap[2], q3 = ap[3];
        ea0 = q0.x * Wf[0][0] + q0.y * Wf[0][1] + q0.z * Wf[0][2] + q0.w * Wf[0][3]
            + q1.x * Wf[0][4] + q1.y * Wf[0][5] + q1.z * Wf[0][6] + q1.w * Wf[0][7]
            + q2.x * Wf[0][8] + q2.y * Wf[0][9] + q2.z * Wf[0][10] + q2.w * Wf[0][11]
            + q3.x * Wf[0][12] + q3.y * Wf[0][13] + q3.z * Wf[0][14] + q3.w * Wf[0][15];
        ea1 = q0.x * Wf[1][0] + q0.y * Wf[1][1] + q0.z * Wf[1][2] + q0.w * Wf[1][3]
            + q1.x * Wf[1][4] + q1.y * Wf[1][5] + q1.z * Wf[1][6] + q1.w * Wf[1][7]
            + q2.x * Wf[1][8] + q2.y * Wf[1][9] + q2.z * Wf[1][10] + q2.w * Wf[1][11]
            + q3.x * Wf[1][12] + q3.y * Wf[1][13] + q3.z * Wf[1][14] + q3.w * Wf[1][15];
        ea2 = q0.x * Wf[2][0] + q0.y * Wf[2][1] + q0.z * Wf[2][2] + q0.w * Wf[2][3]
            + q1.x * Wf[2][4] + q1.y * Wf[2][5] + q1.z * Wf[2][6] + q1.w * Wf[2][7]
            + q2.x * Wf[2][8] + q2.y * Wf[2][9] + q2.z * Wf[2][10] + q2.w * Wf[2][11]
            + q3.x * Wf[2][12] + q3.y * Wf[2][13] + q3.z * Wf[2][14] + q3.w * Wf[2][15];
        ea3 = q0.x * Wf[3][0] + q0.y * Wf[3][1] + q0.z * Wf[3][2] + q0.w * Wf[3][3]
            + q1.x * Wf[3][4] + q1.y * Wf[3][5] + q1.z * Wf[3][6] + q1.w * Wf[3][7]
            + q2.x * Wf[3][8] + q2.y * Wf[3][9] + q2.z * Wf[3][10] + q2.w * Wf[3][11]
            + q3.x * Wf[3][12] + q3.y * Wf[3][13] + q3.z * Wf[3][14] + q3.w * Wf[3][15];
      }
      half2v h0 = u2h(xpk[k].x), h1 = u2h(xpk[k].y);
      float z0 = (float)h0[0] + xr0 + ea0;
      z0 = fmaxf(z0, NEG_SLOPE * z0);
      float z1 = (float)h0[1] + xr1 + ea1;
      z1 = fmaxf(z1, NEG_SLOPE * z1);
      float z2 = (float)h1[0] + xr2 + ea2;
      z2 = fmaxf(z2, NEG_SLOPE * z2);
      float z3 = (float)h1[1] + xr3 + ea3;
      z3 = fmaxf(z3, NEG_SLOPE * z3);
      float p = (z0 * at0 + z1 * at1) + (z2 * at2 + z3 * at3);
      p = row_sum16(p);
      v[k] = msk[k] ? p : -INFINITY;
    }
    float mc = v[0];
#pragma unroll
    for (int k = 1; k < C; k++) mc = fmaxf(mc, v[k]);
    mc = fmaxf(mc, __shfl_xor(mc, 16, 64));
    mc = fmaxf(mc, __shfl_xor(mc, 32, 64));
    float newm = fmaxf(m, mc);
    float s = FEXP(m - newm);  // first chunk: exp(-inf)=0
    l *= s;
    a0 *= s;
    a1 *= s;
    a2 *= s;
    a3 *= s;
#pragma unroll
    for (int k = 0; k < C; k++) {
      float w = FEXP(v[k] - newm);  // masked slots: exp(-inf)=0
      l += w;
      half2v h0 = u2h(xpk[k].x), h1 = u2h(xpk[k].y);
      a0 += w * (float)h0[0];
      a1 += w * (float)h0[1];
      a2 += w * (float)h1[0];
      a3 += w * (float)h1[1];
    }
    m = newm;
  };

  int base = 0;
  for (; base + 16 <= deg; base += 16) chunk(base, IC<4>{});
  if (base + 8 <= deg) {
    chunk(base, IC<2>{});
    base += 8;
  }
  if (base < deg) chunk(base, IC<2>{});  // padded (masks cover rem 1..7)

  // Combine partial l / acc across the 4 edge subgroups (butterfly sums).
  l += __shfl_xor(l, 16, 64);
  l += __shfl_xor(l, 32, 64);
  a0 += __shfl_xor(a0, 16, 64);
  a0 += __shfl_xor(a0, 32, 64);
  a1 += __shfl_xor(a1, 16, 64);
  a1 += __shfl_xor(a1, 32, 64);
  a2 += __shfl_xor(a2, 16, 64);
  a2 += __shfl_xor(a2, 32, 64);
  a3 += __shfl_xor(a3, 16, 64);
  a3 += __shfl_xor(a3, 32, 64);

  if (eg == 0) {
    float den = l + 1e-16f;
    float v0 = a0 / den * sc0 + sh0;
    float v1 = a1 / den * sc1 + sh1;
    float v2 = a2 / den * sc2 + sh2;
    float v3 = a3 / den * sc3 + sh3;
    float g0 = 0.5f * v0 * (1.f + erff(v0 * 0.70710678118654752f));
    float g1 = 0.5f * v1 * (1.f + erff(v1 * 0.70710678118654752f));
    float g2 = 0.5f * v2 * (1.f + erff(v2 * 0.70710678118654752f));
    float g3 = 0.5f * v3 * (1.f + erff(v3 * 0.70710678118654752f));
    float4* hp = (float4*)(h + (size_t)d * 64 + jj * 4);
    float4 o = *hp;
    o.x += g0;
    o.y += g1;
    o.z += g2;
    o.w += g3;
    *hp = o;
  }
}

// ---------------------------------------------------------------------------
// Final: out128 = h @ lin_W.T + lin_b, pooled per graph (round-4 proven).
// ---------------------------------------------------------------------------
__global__ __launch_bounds__(256, 2) void lin_pool_kernel(
    const float* __restrict__ h, const float* __restrict__ lin_W,
    const float* __restrict__ lin_b, const int* __restrict__ batch,
    const float* __restrict__ counts, float* __restrict__ pooled, int rows) {
  __shared__ float shh[4096];
  int lane = threadIdx.x & 63;
  int w = threadIdx.x >> 6;
  int n0 = blockIdx.x * 64;

  {
    int gmax = rows * 64 - 4;
#pragma unroll
    for (int i = 0; i < 4; i++) {
      int off = w * 1024 + i * 256 + lane * 4;
      int g = min(n0 * 64 + off, gmax);
      *(float4*)(shh + off) = *(const float4*)(h + g);
    }
  }

  float4 W0[16], W1[16];
#pragma unroll
  for (int q = 0; q < 16; q++) W0[q] = ((const float4*)(lin_W + lane * 64))[q];
#pragma unroll
  for (int q = 0; q < 16; q++)
    W1[q] = ((const float4*)(lin_W + (lane + 64) * 64))[q];
  float b0 = lin_b[lane], b1 = lin_b[lane + 64];

  int curg = -1;
  float acc0 = 0.f, acc1 = 0.f;
  int lim = min(16, rows - n0 - w * 16);
#pragma unroll 1
  for (int t = 0; t < lim; t++) {
    int r = w * 16 + t;
    __builtin_amdgcn_sched_barrier(0);
    float d0 = b0, d1 = b1;
#pragma unroll
    for (int q = 0; q < 16; q++) {
      float4 v = *(const float4*)(shh + r * 64 + q * 4);
      FMA4(d0, v, W0[q]);
      FMA4(d1, v, W1[q]);
    }
    int g = batch[n0 + r];
    if (g != curg) {
      if (curg >= 0) {
        float inv = 1.f / fmaxf(counts[curg], 1.f);
        atomicAdd(&pooled[curg * 128 + lane], acc0 * inv);
        atomicAdd(&pooled[curg * 128 + 64 + lane], acc1 * inv);
      }
      curg = g;
      acc0 = 0.f;
      acc1 = 0.f;
    }
    acc0 += d0;
    acc1 += d1;
  }
  if (curg >= 0) {
    float inv = 1.f / fmaxf(counts[curg], 1.f);
    atomicAdd(&pooled[curg * 128 + lane], acc0 * inv);
    atomicAdd(&pooled[curg * 128 + 64 + lane], acc1 * inv);
  }
}

extern "C" void kernel_launch(void* const* d_in, const int* in_sizes, int n_in,
                              void* d_out, int out_size, void* d_ws, size_t ws_size,
                              hipStream_t stream) {
  const float* x         = (const float*)d_in[0];
  const int*   edge_index= (const int*)  d_in[1];
  const float* edge_attr = (const float*)d_in[2];
  const int*   batch     = (const int*)  d_in[3];
  const float* emb_W     = (const float*)d_in[4];
  const float* emb_b     = (const float*)d_in[5];
  const float* Wl        = (const float*)d_in[6];
  const float* bl        = (const float*)d_in[7];
  const float* Wr        = (const float*)d_in[8];
  const float* br        = (const float*)d_in[9];
  const float* We        = (const float*)d_in[10];
  const float* att       = (const float*)d_in[11];
  const float* conv_bias = (const float*)d_in[12];
  const float* bn_gamma  = (const float*)d_in[13];
  const float* bn_beta   = (const float*)d_in[14];
  const float* bn_mean   = (const float*)d_in[15];
  const float* bn_var    = (const float*)d_in[16];
  const float* lin_W     = (const float*)d_in[17];
  const float* lin_b     = (const float*)d_in[18];

  const int N_ = in_sizes[0] / 64;
  const int E_ = in_sizes[1] / 2;
  const int G_ = out_size / 128;
  const int* src = edge_index;
  const int* dst = edge_index + E_;

  const int Npad = (N_ + 3) & ~3;
  const int Epad = (E_ + 19) & ~3;
  const int nseg = (N_ + 255) / 256;

  // Workspace layout (floats). xl/xr fp16. w16 = fp16 Wl(3)+Wr(3)+We(3).
  float* ws      = (float*)d_ws;
  float* h       = ws;                                 // N*64
  _Float16* xl   = (_Float16*)(h + (size_t)N_ * 64);   // N*64 halfs
  _Float16* xr   = xl + (size_t)N_ * 64;               // N*64 halfs
  int*   csr_src = (int*)(xr + (size_t)N_ * 64);       // Epad
  int*   csr_eid = csr_src + Epad;                     // Epad
  int*   row_ptr = csr_eid + Epad;                     // Npad+4
  int*   cursor  = row_ptr + (Npad + 4);               // Npad
  int*   deg     = cursor + Npad;                      // Npad
  float* counts  = (float*)(deg + Npad);               // G
  int*   segTot  = (int*)(counts + G_);                // nseg+8
  int*   bins    = segTot + nseg + 8;                  // 128
  int*   perm    = bins + 128;                         // Npad
  uintptr_t abp  = (uintptr_t)(perm + Npad);
  abp = (abp + 15) & ~(uintptr_t)15;
  _Float16* w16  = (_Float16*)abp;                     // 27648 halfs (54KB)
  uintptr_t abp2 = abp + 27648 * sizeof(_Float16);
  abp2 = (abp2 + 15) & ~(uintptr_t)15;
  unsigned* attr_u = (unsigned*)abp2;                  // E*8 uints (optional)

  size_t base_bytes = (abp2 - (uintptr_t)d_ws);
  bool contig = ws_size >= base_bytes + (size_t)E_ * 32 + 64;

  const int hgrid = (max(E_, N_) + 255) / 256;
  const int ngrid = (N_ + 255) / 256;
  const int egrid = (E_ + 255) / 256;

  // --- CSR build + counts + degree-sort + weight pack (fused chain) ---
  hipMemsetAsync(deg, 0, ((size_t)Npad + G_ + nseg + 8 + 128) * 4, stream);
  hist_kernel<<<hgrid, 256, 0, stream>>>(dst, batch, deg, counts, Wl, Wr, We,
                                         w16, E_, N_);
  scanA_kernel<<<min(nseg, 1024), 256, 0, stream>>>(deg, row_ptr, segTot,
                                                    bins, N_, nseg);
  scanB_kernel<<<1, 256, 0, stream>>>(segTot, bins, nseg);
  scanC_kernel<<<ngrid, 256, 0, stream>>>(row_ptr, segTot, cursor, deg, bins,
                                          perm, csr_src, csr_eid, N_, E_);
  scatter_kernel<<<egrid, 256, 0, stream>>>(src, dst, cursor, csr_src,
                                            csr_eid, E_);
  if (contig) {
    permute_attr_kernel<<<egrid, 256, 0, stream>>>(
        (const float4*)edge_attr, csr_eid, attr_u, E_);
  }

  // emb (fp32-exact) + fused layer-0 xl/xr (MFMA from LDS slab)
  const int tgrid = (N_ + 63) / 64;
  emb_kernel<<<tgrid, 256, 0, stream>>>(x, emb_W, emb_b, w16, bl,
                                        w16 + 12288, br, h, xl, xr, N_);

  const int gatBlocks = (N_ + 3) / 4;  // one wave per node
  for (int l = 0; l < 3; l++) {
    if (l > 0) {
      linx_mfma_kernel<<<tgrid, 256, 0, stream>>>(
          h, w16 + (size_t)l * 4096, bl + l * 64,
          w16 + 12288 + (size_t)l * 4096, br + l * 64, xl, xr, N_);
    }
    const _Float16* we16 = w16 + 24576 + (size_t)l * 1024;
    if (contig) {
      gat_fused_kernel<true><<<gatBlocks, 256, 0, stream>>>(
          perm, csr_src, csr_eid, row_ptr, attr_u, edge_attr, xl, xr, we16,
          We + (size_t)l * 1024, att + l * 64, conv_bias + l * 64,
          bn_gamma + l * 64, bn_beta + l * 64, bn_mean + l * 64,
          bn_var + l * 64, h, N_);
    } else {
      gat_fused_kernel<false><<<gatBlocks, 256, 0, stream>>>(
          perm, csr_src, csr_eid, row_ptr, attr_u, edge_attr, xl, xr, we16,
          We + (size_t)l * 1024, att + l * 64, conv_bias + l * 64,
          bn_gamma + l * 64, bn_beta + l * 64, bn_mean + l * 64,
          bn_var + l * 64, h, N_);
    }
  }

  hipMemsetAsync(d_out, 0, (size_t)G_ * 128 * 4, stream);
  lin_pool_kernel<<<(N_ + 63) / 64, 256, 0, stream>>>(
      h, lin_W, lin_b, batch, counts, (float*)d_out, N_);
}

// Round 15
// 543.060 us; speedup vs baseline: 1.1575x; 1.1575x over previous
//
#include <hip/hip_runtime.h>
#include <math.h>

#define NEG_SLOPE 0.2f
#define BN_EPS 1e-5f

template <int N> struct IC { static constexpr int v = N; };
template <bool B> struct BC { static constexpr bool v = B; };

typedef _Float16 half2v __attribute__((ext_vector_type(2)));
typedef _Float16 f16x8 __attribute__((ext_vector_type(8)));
typedef float f32x4v __attribute__((ext_vector_type(4)));

__device__ __forceinline__ half2v u2h(unsigned u) {
  union { unsigned u; half2v h; } c;
  c.u = u;
  return c.h;
}
__device__ __forceinline__ unsigned pkh(float lo, float hi) {
  union { half2v h; unsigned u; } c;
  c.h[0] = (_Float16)lo;
  c.h[1] = (_Float16)hi;
  return c.u;
}

#if defined(__has_builtin)
#if __has_builtin(__builtin_amdgcn_fdot2)
#define FDOT2(a, b, c) __builtin_amdgcn_fdot2((a), (b), (c), false)
#endif
#endif
#ifndef FDOT2
__device__ __forceinline__ float fdot2_sw(half2v a, half2v b, float c) {
  return c + (float)a[0] * (float)b[0] + (float)a[1] * (float)b[1];
}
#define FDOT2(a, b, c) fdot2_sw((a), (b), (c))
#endif

// Fast exp: raw v_exp_f32 (2^x) with att pre-scaled by log2(e).
#if defined(__has_builtin)
#if __has_builtin(__builtin_amdgcn_exp2f)
#define FEXP(x) __builtin_amdgcn_exp2f(x)
#define ATT_SCALE 1.44269504088896f
#endif
#endif
#ifndef FEXP
#define FEXP(x) __expf(x)
#define ATT_SCALE 1.0f
#endif

// FMA of one float4 pair into scalar accumulator (expanded inline at use).
#define FMA4(acc, v, wq) \
  acc += (v).x * (wq).x + (v).y * (wq).y + (v).z * (wq).z + (v).w * (wq).w

// One 64-dot row-pass against register-resident W[16] (float4).
// sched_barrier(0) fences the scheduler (round-4 proven; no spills).
#define DOT_ROW(buf, stride, r, bias, OUT)                                  \
  {                                                                         \
    __builtin_amdgcn_sched_barrier(0);                                      \
    float a0 = 0.f, a1 = 0.f, a2 = 0.f, a3 = 0.f;                           \
    _Pragma("unroll") for (int q = 0; q < 4; q++) {                         \
      float4 v0 = *(const float4*)((buf) + (r) * (stride) + q * 16 + 0);    \
      float4 v1 = *(const float4*)((buf) + (r) * (stride) + q * 16 + 4);    \
      float4 v2 = *(const float4*)((buf) + (r) * (stride) + q * 16 + 8);    \
      float4 v3 = *(const float4*)((buf) + (r) * (stride) + q * 16 + 12);   \
      FMA4(a0, v0, W[q * 4 + 0]);                                           \
      FMA4(a1, v1, W[q * 4 + 1]);                                           \
      FMA4(a2, v2, W[q * 4 + 2]);                                           \
      FMA4(a3, v3, W[q * 4 + 3]);                                           \
    }                                                                       \
    OUT = (bias) + ((a0 + a1) + (a2 + a3));                                 \
  }

// ---------------------------------------------------------------------------
// VALU-only 64-lane sum, zero LDS ops (round-6 proven).
// ---------------------------------------------------------------------------
__device__ __forceinline__ float wave_sum64(float v) {
  int x;
  x = __builtin_amdgcn_update_dpp(0, __float_as_int(v), 0x121, 0xF, 0xF, true);
  v += __int_as_float(x);  // row_ror:1
  x = __builtin_amdgcn_update_dpp(0, __float_as_int(v), 0x122, 0xF, 0xF, true);
  v += __int_as_float(x);  // row_ror:2
  x = __builtin_amdgcn_update_dpp(0, __float_as_int(v), 0x124, 0xF, 0xF, true);
  v += __int_as_float(x);  // row_ror:4
  x = __builtin_amdgcn_update_dpp(0, __float_as_int(v), 0x128, 0xF, 0xF, true);
  v += __int_as_float(x);  // row_ror:8
  x = __builtin_amdgcn_update_dpp(0, __float_as_int(v), 0x142, 0xF, 0xF, true);
  v += __int_as_float(x);  // row_bcast15
  x = __builtin_amdgcn_update_dpp(0, __float_as_int(v), 0x143, 0xF, 0xF, true);
  v += __int_as_float(x);  // row_bcast31: lanes48-63 = total
  return __int_as_float(__builtin_amdgcn_readlane(__float_as_int(v), 63));
}

#if defined(__has_builtin)
#if __has_builtin(__builtin_amdgcn_mfma_f32_16x16x32_f16)
#define HAVE_MFMA16 1
#endif
#endif

// ---------------------------------------------------------------------------
// hist + graph-counts + fp16 weight pack (all independent, one launch).
// ---------------------------------------------------------------------------
__global__ __launch_bounds__(256) void hist_kernel(
    const int* __restrict__ dst, const int* __restrict__ batch,
    int* __restrict__ deg, float* __restrict__ counts,
    const float* __restrict__ Wl, const float* __restrict__ Wr,
    _Float16* __restrict__ w16, int E_, int N_) {
  int i = blockIdx.x * 256 + threadIdx.x;
  if (i < E_) atomicAdd(&deg[dst[i]], 1);
  if (i < N_) atomicAdd(&counts[batch[i]], 1.0f);
  if (i < 24576)
    w16[i] = (i < 12288) ? (_Float16)Wl[i] : (_Float16)Wr[i - 12288];
}

// ---------------------------------------------------------------------------
// scanA: per-256-segment local prefix + totals; FUSED degree histogram
// (128 bins, DESCENDING degree, LDS-aggregated).
// ---------------------------------------------------------------------------
__global__ __launch_bounds__(256) void scanA_kernel(
    const int* __restrict__ deg, int* __restrict__ row_ptr,
    int* __restrict__ segTot, int* __restrict__ bins, int N_, int nseg) {
  __shared__ int sb[256];
  __shared__ int lb[128];
  int t = threadIdx.x;
  if (t < 128) lb[t] = 0;
  __syncthreads();
  for (int s = blockIdx.x; s < nseg; s += gridDim.x) {
    int i = s * 256 + t;
    int v = (i < N_) ? deg[i] : 0;
    if (i < N_) atomicAdd(&lb[127 - min(v, 127)], 1);
    sb[t] = v;
    __syncthreads();
    for (int off = 1; off < 256; off <<= 1) {
      int a = (t >= off) ? sb[t - off] : 0;
      __syncthreads();
      sb[t] += a;
      __syncthreads();
    }
    int incl = sb[t];
    if (i < N_) row_ptr[i] = incl - v;
    if (t == 255) segTot[s] = incl;
    __syncthreads();
  }
  if (t < 128 && lb[t]) atomicAdd(&bins[t], lb[t]);
}

// ---------------------------------------------------------------------------
// scanB: scan segTot; FUSED exclusive scan of the 128 degree bins.
// ---------------------------------------------------------------------------
__global__ __launch_bounds__(256) void scanB_kernel(int* __restrict__ segTot,
                                                    int* __restrict__ bins,
                                                    int nseg) {
  __shared__ int sb[256];
  __shared__ int baseSh;
  int t = threadIdx.x;
  if (t == 0) baseSh = 0;
  __syncthreads();
  for (int c0 = 0; c0 < nseg; c0 += 256) {
    int s = c0 + t;
    int v = (s < nseg) ? segTot[s] : 0;
    sb[t] = v;
    __syncthreads();
    for (int off = 1; off < 256; off <<= 1) {
      int a = (t >= off) ? sb[t - off] : 0;
      __syncthreads();
      sb[t] += a;
      __syncthreads();
    }
    int incl = sb[t];
    int base = baseSh;
    if (s < nseg) segTot[s] = base + incl - v;
    __syncthreads();
    if (t == 255) baseSh = base + incl;
    __syncthreads();
  }
  int v2 = (t < 128) ? bins[t] : 0;
  sb[t] = v2;
  __syncthreads();
  for (int off = 1; off < 256; off <<= 1) {
    int a = (t >= off) ? sb[t - off] : 0;
    __syncthreads();
    sb[t] += a;
    __syncthreads();
  }
  if (t < 128) bins[t] = sb[t] - v2;
}

// ---------------------------------------------------------------------------
// scanC: finalize row_ptr/cursor; FUSED degree-sort scatter; zero csr pads.
// ---------------------------------------------------------------------------
__global__ __launch_bounds__(256) void scanC_kernel(
    int* __restrict__ row_ptr, const int* __restrict__ segTot,
    int* __restrict__ cursor, const int* __restrict__ deg,
    int* __restrict__ bins, int* __restrict__ perm,
    int* __restrict__ csr_src, int* __restrict__ csr_eid, int N_, int E_) {
  __shared__ int lb[128];
  __shared__ int lbase[128];
  int t = threadIdx.x;
  if (t < 128) lb[t] = 0;
  __syncthreads();
  int i = blockIdx.x * 256 + t;
  int bin = 0, rk = 0;
  bool ok = (i < N_);
  if (ok) {
    int rp = row_ptr[i] + segTot[i >> 8];
    row_ptr[i] = rp;
    cursor[i] = rp;
    int dg = deg[i];
    bin = 127 - min(dg, 127);
    rk = atomicAdd(&lb[bin], 1);
  }
  if (i == 0) row_ptr[N_] = E_;
  if (blockIdx.x == 0 && t < 16) {
    csr_src[E_ + t] = 0;
    csr_eid[E_ + t] = 0;
  }
  __syncthreads();
  if (t < 128) {
    int c = lb[t];
    lbase[t] = c ? atomicAdd(&bins[t], c) : 0;
  }
  __syncthreads();
  if (ok) perm[lbase[bin] + rk] = i;
}

// ---------------------------------------------------------------------------
// Scatter: 4B-only random writes (L2-resident).
// ---------------------------------------------------------------------------
__global__ __launch_bounds__(256) void scatter_kernel(
    const int* __restrict__ src, const int* __restrict__ dst,
    int* __restrict__ cursor, int* __restrict__ csr_src,
    int* __restrict__ csr_eid, int E_) {
  int e = blockIdx.x * 256 + threadIdx.x;
  if (e >= E_) return;
  int pos = atomicAdd(&cursor[dst[e]], 1);
  csr_src[pos] = src[e];
  csr_eid[pos] = e;
}

// ---------------------------------------------------------------------------
// Permute+convert attr: sequential coalesced 32B writes; random 64B-line
// gathers (each line read exactly once).
// ---------------------------------------------------------------------------
__global__ __launch_bounds__(256) void permute_attr_kernel(
    const float4* __restrict__ edge_attr4, const int* __restrict__ csr_eid,
    unsigned* __restrict__ attr_u, int E_) {
  int p = blockIdx.x * 256 + threadIdx.x;
  if (p >= E_) return;
  int e = csr_eid[p];
  float4 a0 = edge_attr4[(size_t)e * 4 + 0];
  float4 a1 = edge_attr4[(size_t)e * 4 + 1];
  float4 a2 = edge_attr4[(size_t)e * 4 + 2];
  float4 a3 = edge_attr4[(size_t)e * 4 + 3];
  uint4 u0, u1;
  u0.x = pkh(a0.x, a0.y);
  u0.y = pkh(a0.z, a0.w);
  u0.z = pkh(a1.x, a1.y);
  u0.w = pkh(a1.z, a1.w);
  u1.x = pkh(a2.x, a2.y);
  u1.y = pkh(a2.z, a2.w);
  u1.z = pkh(a3.x, a3.y);
  u1.w = pkh(a3.z, a3.w);
  uint4* d4 = (uint4*)(attr_u + (size_t)p * 8);
  d4[0] = u0;
  d4[1] = u1;
}

// ---------------------------------------------------------------------------
// emb + FUSED layer-0 linx (round-11 proven).
// ---------------------------------------------------------------------------
__global__ __launch_bounds__(256, 3) void emb_kernel(
    const float* __restrict__ x, const float* __restrict__ emb_W,
    const float* __restrict__ emb_b, const _Float16* __restrict__ Wl16,
    const float* __restrict__ bl, const _Float16* __restrict__ Wr16,
    const float* __restrict__ br, float* __restrict__ h,
    _Float16* __restrict__ xl, _Float16* __restrict__ xr, int rows) {
  __shared__ float sx[4096];
  __shared__ float sh[64 * 68];
  int lane = threadIdx.x & 63;
  int w = threadIdx.x >> 6;
  int n0 = blockIdx.x * 64;

  {
    int gmax = rows * 64 - 4;
#pragma unroll
    for (int i = 0; i < 4; i++) {
      int off = w * 1024 + i * 256 + lane * 4;
      int g = min(n0 * 64 + off, gmax);
      *(float4*)(sx + off) = *(const float4*)(x + g);
    }
  }

  {
    float4 W[16];
#pragma unroll
    for (int q = 0; q < 16; q++) W[q] = ((const float4*)(emb_W + lane * 64))[q];
    float b = emb_b[lane];
#pragma unroll 1
    for (int t = 0; t < 16; t++) {
      int r = w * 16 + t;
      float a;
      DOT_ROW(sx, 64, r, b, a);
      sh[r * 68 + lane] = a;
      int n = n0 + r;
      if (n < rows) h[(size_t)n * 64 + lane] = a;
    }
  }

#ifdef HAVE_MFMA16
  {
    int r = lane & 15;
    int kg = lane >> 4;
    int nb = n0 + w * 16;
    const float* p = sh + (w * 16 + r) * 68 + kg * 8;
    f16x8 A0, A1;
    {
      float4 xa = *(const float4*)(p);
      float4 xb = *(const float4*)(p + 4);
      A0[0] = (_Float16)xa.x; A0[1] = (_Float16)xa.y;
      A0[2] = (_Float16)xa.z; A0[3] = (_Float16)xa.w;
      A0[4] = (_Float16)xb.x; A0[5] = (_Float16)xb.y;
      A0[6] = (_Float16)xb.z; A0[7] = (_Float16)xb.w;
      xa = *(const float4*)(p + 32);
      xb = *(const float4*)(p + 36);
      A1[0] = (_Float16)xa.x; A1[1] = (_Float16)xa.y;
      A1[2] = (_Float16)xa.z; A1[3] = (_Float16)xa.w;
      A1[4] = (_Float16)xb.x; A1[5] = (_Float16)xb.y;
      A1[6] = (_Float16)xb.z; A1[7] = (_Float16)xb.w;
    }
#pragma unroll
    for (int c = 0; c < 4; c++) {
      int o = c * 16 + r;
      {
        const f16x8* b0 = (const f16x8*)(Wl16 + (size_t)o * 64 + kg * 8);
        const f16x8* b1 = (const f16x8*)(Wl16 + (size_t)o * 64 + 32 + kg * 8);
        f32x4v acc;
        float bv = bl[o];
        acc[0] = bv; acc[1] = bv; acc[2] = bv; acc[3] = bv;
        acc = __builtin_amdgcn_mfma_f32_16x16x32_f16(A0, b0[0], acc, 0, 0, 0);
        acc = __builtin_amdgcn_mfma_f32_16x16x32_f16(A1, b1[0], acc, 0, 0, 0);
#pragma unroll
        for (int g = 0; g < 4; g++) {
          int nd = nb + kg * 4 + g;
          if (nd < rows) xl[(size_t)nd * 64 + o] = (_Float16)acc[g];
        }
      }
      {
        const f16x8* b0 = (const f16x8*)(Wr16 + (size_t)o * 64 + kg * 8);
        const f16x8* b1 = (const f16x8*)(Wr16 + (size_t)o * 64 + 32 + kg * 8);
        f32x4v acc;
        float bv = br[o];
        acc[0] = bv; acc[1] = bv; acc[2] = bv; acc[3] = bv;
        acc = __builtin_amdgcn_mfma_f32_16x16x32_f16(A0, b0[0], acc, 0, 0, 0);
        acc = __builtin_amdgcn_mfma_f32_16x16x32_f16(A1, b1[0], acc, 0, 0, 0);
#pragma unroll
        for (int g = 0; g < 4; g++) {
          int nd = nb + kg * 4 + g;
          if (nd < rows) xr[(size_t)nd * 64 + o] = (_Float16)acc[g];
        }
      }
    }
  }
#endif
}

// ---------------------------------------------------------------------------
// linx via MFMA (round-8 proven). Layers 1,2.
// ---------------------------------------------------------------------------
__global__ __launch_bounds__(256) void linx_mfma_kernel(
    const float* __restrict__ in, const _Float16* __restrict__ Wl16,
    const float* __restrict__ bl, const _Float16* __restrict__ Wr16,
    const float* __restrict__ br, _Float16* __restrict__ xl,
    _Float16* __restrict__ xr, int rows) {
#ifdef HAVE_MFMA16
  int lane = threadIdx.x & 63;
  int w = threadIdx.x >> 6;
  int n0 = blockIdx.x * 64 + w * 16;
  int r = lane & 15;
  int kg = lane >> 4;

  int nA = min(n0 + r, rows - 1);
  f16x8 A0, A1;
  {
    const float* p = in + (size_t)nA * 64 + kg * 8;
    float4 xa = *(const float4*)(p);
    float4 xb = *(const float4*)(p + 4);
    A0[0] = (_Float16)xa.x; A0[1] = (_Float16)xa.y;
    A0[2] = (_Float16)xa.z; A0[3] = (_Float16)xa.w;
    A0[4] = (_Float16)xb.x; A0[5] = (_Float16)xb.y;
    A0[6] = (_Float16)xb.z; A0[7] = (_Float16)xb.w;
    xa = *(const float4*)(p + 32);
    xb = *(const float4*)(p + 36);
    A1[0] = (_Float16)xa.x; A1[1] = (_Float16)xa.y;
    A1[2] = (_Float16)xa.z; A1[3] = (_Float16)xa.w;
    A1[4] = (_Float16)xb.x; A1[5] = (_Float16)xb.y;
    A1[6] = (_Float16)xb.z; A1[7] = (_Float16)xb.w;
  }

#pragma unroll
  for (int c = 0; c < 4; c++) {
    int o = c * 16 + r;
    {
      const f16x8* b0 = (const f16x8*)(Wl16 + (size_t)o * 64 + kg * 8);
      const f16x8* b1 = (const f16x8*)(Wl16 + (size_t)o * 64 + 32 + kg * 8);
      f32x4v acc;
      float bv = bl[o];
      acc[0] = bv; acc[1] = bv; acc[2] = bv; acc[3] = bv;
      acc = __builtin_amdgcn_mfma_f32_16x16x32_f16(A0, b0[0], acc, 0, 0, 0);
      acc = __builtin_amdgcn_mfma_f32_16x16x32_f16(A1, b1[0], acc, 0, 0, 0);
#pragma unroll
      for (int g = 0; g < 4; g++) {
        int nd = n0 + kg * 4 + g;
        if (nd < rows) xl[(size_t)nd * 64 + o] = (_Float16)acc[g];
      }
    }
    {
      const f16x8* b0 = (const f16x8*)(Wr16 + (size_t)o * 64 + kg * 8);
      const f16x8* b1 = (const f16x8*)(Wr16 + (size_t)o * 64 + 32 + kg * 8);
      f32x4v acc;
      float bv = br[o];
      acc[0] = bv; acc[1] = bv; acc[2] = bv; acc[3] = bv;
      acc = __builtin_amdgcn_mfma_f32_16x16x32_f16(A0, b0[0], acc, 0, 0, 0);
      acc = __builtin_amdgcn_mfma_f32_16x16x32_f16(A1, b1[0], acc, 0, 0, 0);
#pragma unroll
      for (int g = 0; g < 4; g++) {
        int nd = n0 + kg * 4 + g;
        if (nd < rows) xr[(size_t)nd * 64 + o] = (_Float16)acc[g];
      }
    }
  }
#endif
}

// ---------------------------------------------------------------------------
// Fused GATv2 layer (round-11/13 proven — best measured): one wave per
// (degree-sorted) node; 16/8/4-full + 4-padded chunks; scalar csr_src
// (readfirstlane -> SALU addressing); wave-uniform attr s_loads; fp16 xl
// gathers; ea via fdot2; LDS-free DPP reduction; online-max softmax via raw
// v_exp_f32 (exp2 domain). Epilogue = folded conv_bias+BN, exact GELU,
// residual.
// ---------------------------------------------------------------------------
template <bool CONTIG>
__global__ __launch_bounds__(256) void gat_fused_kernel(
    const int* __restrict__ perm, const int* __restrict__ csr_src,
    const int* __restrict__ csr_eid, const int* __restrict__ row_ptr,
    const unsigned* __restrict__ attr_u, const float* __restrict__ edge_attr,
    const _Float16* __restrict__ xl, const _Float16* __restrict__ xr,
    const float* __restrict__ We, const float* __restrict__ att,
    const float* __restrict__ conv_bias, const float* __restrict__ gamma,
    const float* __restrict__ beta, const float* __restrict__ mean,
    const float* __restrict__ var, float* __restrict__ h, int N_) {
  int widx = (blockIdx.x * 256 + threadIdx.x) >> 6;
  if (widx >= N_) return;
  int d = __builtin_amdgcn_readfirstlane(perm[widx]);
  int j = threadIdx.x & 63;
  half2v Wek2[8];
  float Wekf[16];
  if constexpr (CONTIG) {
#pragma unroll
    for (int q = 0; q < 8; q++) {
      Wek2[q][0] = (_Float16)We[j * 16 + 2 * q];
      Wek2[q][1] = (_Float16)We[j * 16 + 2 * q + 1];
    }
  } else {
#pragma unroll
    for (int k = 0; k < 16; k++) Wekf[k] = We[j * 16 + k];
  }
  float att_j = att[j] * ATT_SCALE;
  float sc = rsqrtf(var[j] + BN_EPS) * gamma[j];
  float sh = (conv_bias[j] - mean[j]) * sc + beta[j];

  int beg = __builtin_amdgcn_readfirstlane(row_ptr[d]);
  int end = __builtin_amdgcn_readfirstlane(row_ptr[d + 1]);
  float xrj = (float)xr[(size_t)d * 64 + j];
  float m = -INFINITY, l = 0.f, acc = 0.f;

  auto chunk = [&](int base, auto C_, auto PAD_) {
    constexpr int C = decltype(C_)::v;
    constexpr bool PAD = decltype(PAD_)::v;
    int si[C];
#pragma unroll
    for (int t = 0; t < C; t++) {
      int idx = PAD ? min(base + t, end - 1) : (base + t);
      si[t] = __builtin_amdgcn_readfirstlane(csr_src[idx]);  // SGPR -> SALU addr
    }
    float xlv[C];
#pragma unroll
    for (int t = 0; t < C; t++)
      xlv[t] = (float)xl[(size_t)si[t] * 64 + j];
    float v[C];
#pragma unroll
    for (int t = 0; t < C; t++) {
      int idx = PAD ? min(base + t, end - 1) : (base + t);
      float ea;
      if constexpr (CONTIG) {
        const uint4* ap = (const uint4*)(attr_u + (size_t)idx * 8);
        uint4 ua = ap[0], ub = ap[1];  // uniform -> s_load_dwordx4
        ea = 0.f;
        ea = FDOT2(u2h(ua.x), Wek2[0], ea);
        ea = FDOT2(u2h(ua.y), Wek2[1], ea);
        ea = FDOT2(u2h(ua.z), Wek2[2], ea);
        ea = FDOT2(u2h(ua.w), Wek2[3], ea);
        ea = FDOT2(u2h(ub.x), Wek2[4], ea);
        ea = FDOT2(u2h(ub.y), Wek2[5], ea);
        ea = FDOT2(u2h(ub.z), Wek2[6], ea);
        ea = FDOT2(u2h(ub.w), Wek2[7], ea);
      } else {
        const float4* ap =
            (const float4*)(edge_attr + (size_t)csr_eid[idx] * 16);
        float4 a0 = ap[0], a1 = ap[1], a2 = ap[2], a3 = ap[3];
        ea = a0.x * Wekf[0]  + a0.y * Wekf[1]  + a0.z * Wekf[2]  + a0.w * Wekf[3]
           + a1.x * Wekf[4]  + a1.y * Wekf[5]  + a1.z * Wekf[6]  + a1.w * Wekf[7]
           + a2.x * Wekf[8]  + a2.y * Wekf[9]  + a2.z * Wekf[10] + a2.w * Wekf[11]
           + a3.x * Wekf[12] + a3.y * Wekf[13] + a3.z * Wekf[14] + a3.w * Wekf[15];
      }
      float z = xlv[t] + xrj + ea;
      z = fmaxf(z, NEG_SLOPE * z);  // leaky_relu
      float p = wave_sum64(z * att_j);
      v[t] = (!PAD || (base + t < end)) ? p : -INFINITY;
    }
    float mc = v[0];
#pragma unroll
    for (int t = 1; t < C; t++) mc = fmaxf(mc, v[t]);
    float newm = fmaxf(m, mc);
    float s = FEXP(m - newm);  // first chunk: exp(-inf)=0
    l *= s;
    acc *= s;
#pragma unroll
    for (int t = 0; t < C; t++) {
      float w = FEXP(v[t] - newm);  // masked slots: exp(-inf)=0
      l += w;
      acc += w * xlv[t];
    }
    m = newm;
  };

  int base = beg;
  for (; base + 16 <= end; base += 16) chunk(base, IC<16>{}, BC<false>{});
  if (base + 8 <= end) {
    chunk(base, IC<8>{}, BC<false>{});
    base += 8;
  }
  if (base + 4 <= end) {
    chunk(base, IC<4>{}, BC<false>{});
    base += 4;
  }
  if (base < end) chunk(base, IC<4>{}, BC<true>{});

  float val = acc / (l + 1e-16f) * sc + sh;  // conv_bias+BN folded
  float g = 0.5f * val * (1.f + erff(val * 0.70710678118654752f));
  h[(size_t)d * 64 + j] += g;
}

// ---------------------------------------------------------------------------
// Final: out128 = h @ lin_W.T + lin_b, pooled per graph (round-4 proven).
// ---------------------------------------------------------------------------
__global__ __launch_bounds__(256, 2) void lin_pool_kernel(
    const float* __restrict__ h, const float* __restrict__ lin_W,
    const float* __restrict__ lin_b, const int* __restrict__ batch,
    const float* __restrict__ counts, float* __restrict__ pooled, int rows) {
  __shared__ float shh[4096];
  int lane = threadIdx.x & 63;
  int w = threadIdx.x >> 6;
  int n0 = blockIdx.x * 64;

  {
    int gmax = rows * 64 - 4;
#pragma unroll
    for (int i = 0; i < 4; i++) {
      int off = w * 1024 + i * 256 + lane * 4;
      int g = min(n0 * 64 + off, gmax);
      *(float4*)(shh + off) = *(const float4*)(h + g);
    }
  }

  float4 W0[16], W1[16];
#pragma unroll
  for (int q = 0; q < 16; q++) W0[q] = ((const float4*)(lin_W + lane * 64))[q];
#pragma unroll
  for (int q = 0; q < 16; q++)
    W1[q] = ((const float4*)(lin_W + (lane + 64) * 64))[q];
  float b0 = lin_b[lane], b1 = lin_b[lane + 64];

  int curg = -1;
  float acc0 = 0.f, acc1 = 0.f;
  int lim = min(16, rows - n0 - w * 16);
#pragma unroll 1
  for (int t = 0; t < lim; t++) {
    int r = w * 16 + t;
    __builtin_amdgcn_sched_barrier(0);
    float d0 = b0, d1 = b1;
#pragma unroll
    for (int q = 0; q < 16; q++) {
      float4 v = *(const float4*)(shh + r * 64 + q * 4);
      FMA4(d0, v, W0[q]);
      FMA4(d1, v, W1[q]);
    }
    int g = batch[n0 + r];
    if (g != curg) {
      if (curg >= 0) {
        float inv = 1.f / fmaxf(counts[curg], 1.f);
        atomicAdd(&pooled[curg * 128 + lane], acc0 * inv);
        atomicAdd(&pooled[curg * 128 + 64 + lane], acc1 * inv);
      }
      curg = g;
      acc0 = 0.f;
      acc1 = 0.f;
    }
    acc0 += d0;
    acc1 += d1;
  }
  if (curg >= 0) {
    float inv = 1.f / fmaxf(counts[curg], 1.f);
    atomicAdd(&pooled[curg * 128 + lane], acc0 * inv);
    atomicAdd(&pooled[curg * 128 + 64 + lane], acc1 * inv);
  }
}

extern "C" void kernel_launch(void* const* d_in, const int* in_sizes, int n_in,
                              void* d_out, int out_size, void* d_ws, size_t ws_size,
                              hipStream_t stream) {
  const float* x         = (const float*)d_in[0];
  const int*   edge_index= (const int*)  d_in[1];
  const float* edge_attr = (const float*)d_in[2];
  const int*   batch     = (const int*)  d_in[3];
  const float* emb_W     = (const float*)d_in[4];
  const float* emb_b     = (const float*)d_in[5];
  const float* Wl        = (const float*)d_in[6];
  const float* bl        = (const float*)d_in[7];
  const float* Wr        = (const float*)d_in[8];
  const float* br        = (const float*)d_in[9];
  const float* We        = (const float*)d_in[10];
  const float* att       = (const float*)d_in[11];
  const float* conv_bias = (const float*)d_in[12];
  const float* bn_gamma  = (const float*)d_in[13];
  const float* bn_beta   = (const float*)d_in[14];
  const float* bn_mean   = (const float*)d_in[15];
  const float* bn_var    = (const float*)d_in[16];
  const float* lin_W     = (const float*)d_in[17];
  const float* lin_b     = (const float*)d_in[18];

  const int N_ = in_sizes[0] / 64;
  const int E_ = in_sizes[1] / 2;
  const int G_ = out_size / 128;
  const int* src = edge_index;
  const int* dst = edge_index + E_;

  const int Npad = (N_ + 3) & ~3;
  const int Epad = (E_ + 19) & ~3;
  const int nseg = (N_ + 255) / 256;

  // Workspace layout (floats). xl/xr fp16. w16 = fp16 Wl(3)+Wr(3) packed.
  float* ws      = (float*)d_ws;
  float* h       = ws;                                 // N*64
  _Float16* xl   = (_Float16*)(h + (size_t)N_ * 64);   // N*64 halfs
  _Float16* xr   = xl + (size_t)N_ * 64;               // N*64 halfs
  int*   csr_src = (int*)(xr + (size_t)N_ * 64);       // Epad
  int*   csr_eid = csr_src + Epad;                     // Epad
  int*   row_ptr = csr_eid + Epad;                     // Npad+4
  int*   cursor  = row_ptr + (Npad + 4);               // Npad
  int*   deg     = cursor + Npad;                      // Npad
  float* counts  = (float*)(deg + Npad);               // G
  int*   segTot  = (int*)(counts + G_);                // nseg+8
  int*   bins    = segTot + nseg + 8;                  // 128
  int*   perm    = bins + 128;                         // Npad
  uintptr_t abp  = (uintptr_t)(perm + Npad);
  abp = (abp + 15) & ~(uintptr_t)15;
  _Float16* w16  = (_Float16*)abp;                     // 24576 halfs (48KB)
  uintptr_t abp2 = abp + 24576 * sizeof(_Float16);
  unsigned* attr_u = (unsigned*)abp2;                  // E*8 uints (optional)

  size_t base_bytes = (abp2 - (uintptr_t)d_ws);
  bool contig = ws_size >= base_bytes + (size_t)E_ * 32 + 64;

  const int hgrid = (max(E_, N_) + 255) / 256;
  const int ngrid = (N_ + 255) / 256;
  const int egrid = (E_ + 255) / 256;

  // --- CSR build + counts + degree-sort + weight pack (fused chain) ---
  hipMemsetAsync(deg, 0, ((size_t)Npad + G_ + nseg + 8 + 128) * 4, stream);
  hist_kernel<<<hgrid, 256, 0, stream>>>(dst, batch, deg, counts, Wl, Wr,
                                         w16, E_, N_);
  scanA_kernel<<<min(nseg, 1024), 256, 0, stream>>>(deg, row_ptr, segTot,
                                                    bins, N_, nseg);
  scanB_kernel<<<1, 256, 0, stream>>>(segTot, bins, nseg);
  scanC_kernel<<<ngrid, 256, 0, stream>>>(row_ptr, segTot, cursor, deg, bins,
                                          perm, csr_src, csr_eid, N_, E_);
  scatter_kernel<<<egrid, 256, 0, stream>>>(src, dst, cursor, csr_src,
                                            csr_eid, E_);
  if (contig) {
    permute_attr_kernel<<<egrid, 256, 0, stream>>>(
        (const float4*)edge_attr, csr_eid, attr_u, E_);
  }

  // emb (fp32-exact) + fused layer-0 xl/xr (MFMA from LDS slab)
  const int tgrid = (N_ + 63) / 64;
  emb_kernel<<<tgrid, 256, 0, stream>>>(x, emb_W, emb_b, w16, bl,
                                        w16 + 12288, br, h, xl, xr, N_);

  const int gatBlocks = (N_ + 3) / 4;  // one wave per node
  for (int l = 0; l < 3; l++) {
    if (l > 0) {
      linx_mfma_kernel<<<tgrid, 256, 0, stream>>>(
          h, w16 + (size_t)l * 4096, bl + l * 64,
          w16 + 12288 + (size_t)l * 4096, br + l * 64, xl, xr, N_);
    }
    if (contig) {
      gat_fused_kernel<true><<<gatBlocks, 256, 0, stream>>>(
          perm, csr_src, csr_eid, row_ptr, attr_u, edge_attr, xl, xr,
          We + (size_t)l * 1024, att + l * 64, conv_bias + l * 64,
          bn_gamma + l * 64, bn_beta + l * 64, bn_mean + l * 64,
          bn_var + l * 64, h, N_);
    } else {
      gat_fused_kernel<false><<<gatBlocks, 256, 0, stream>>>(
          perm, csr_src, csr_eid, row_ptr, attr_u, edge_attr, xl, xr,
          We + (size_t)l * 1024, att + l * 64, conv_bias + l * 64,
          bn_gamma + l * 64, bn_beta + l * 64, bn_mean + l * 64,
          bn_var + l * 64, h, N_);
    }
  }

  hipMemsetAsync(d_out, 0, (size_t)G_ * 128 * 4, stream);
  lin_pool_kernel<<<(N_ + 63) / 64, 256, 0, stream>>>(
      h, lin_W, lin_b, batch, counts, (float*)d_out, N_);
}

// Round 16
// 513.512 us; speedup vs baseline: 1.2241x; 1.0575x over previous
//
#include <hip/hip_runtime.h>
#include <math.h>

#define NEG_SLOPE 0.2f
#define BN_EPS 1e-5f

template <int N> struct IC { static constexpr int v = N; };
template <bool B> struct BC { static constexpr bool v = B; };

typedef _Float16 half2v __attribute__((ext_vector_type(2)));
typedef _Float16 f16x8 __attribute__((ext_vector_type(8)));
typedef float f32x4v __attribute__((ext_vector_type(4)));

__device__ __forceinline__ half2v u2h(unsigned u) {
  union { unsigned u; half2v h; } c;
  c.u = u;
  return c.h;
}
__device__ __forceinline__ unsigned pkh(float lo, float hi) {
  union { half2v h; unsigned u; } c;
  c.h[0] = (_Float16)lo;
  c.h[1] = (_Float16)hi;
  return c.u;
}

#if defined(__has_builtin)
#if __has_builtin(__builtin_amdgcn_fdot2)
#define FDOT2(a, b, c) __builtin_amdgcn_fdot2((a), (b), (c), false)
#endif
#endif
#ifndef FDOT2
__device__ __forceinline__ float fdot2_sw(half2v a, half2v b, float c) {
  return c + (float)a[0] * (float)b[0] + (float)a[1] * (float)b[1];
}
#define FDOT2(a, b, c) fdot2_sw((a), (b), (c))
#endif

// Fast exp: raw v_exp_f32 (2^x) with att pre-scaled by log2(e).
#if defined(__has_builtin)
#if __has_builtin(__builtin_amdgcn_exp2f)
#define FEXP(x) __builtin_amdgcn_exp2f(x)
#define ATT_SCALE 1.44269504088896f
#endif
#endif
#ifndef FEXP
#define FEXP(x) __expf(x)
#define ATT_SCALE 1.0f
#endif

// FMA of one float4 pair into scalar accumulator (expanded inline at use).
#define FMA4(acc, v, wq) \
  acc += (v).x * (wq).x + (v).y * (wq).y + (v).z * (wq).z + (v).w * (wq).w

// One 64-dot row-pass against register-resident W[16] (float4).
// sched_barrier(0) fences the scheduler (round-4 proven; no spills).
#define DOT_ROW(buf, stride, r, bias, OUT)                                  \
  {                                                                         \
    __builtin_amdgcn_sched_barrier(0);                                      \
    float a0 = 0.f, a1 = 0.f, a2 = 0.f, a3 = 0.f;                           \
    _Pragma("unroll") for (int q = 0; q < 4; q++) {                         \
      float4 v0 = *(const float4*)((buf) + (r) * (stride) + q * 16 + 0);    \
      float4 v1 = *(const float4*)((buf) + (r) * (stride) + q * 16 + 4);    \
      float4 v2 = *(const float4*)((buf) + (r) * (stride) + q * 16 + 8);    \
      float4 v3 = *(const float4*)((buf) + (r) * (stride) + q * 16 + 12);   \
      FMA4(a0, v0, W[q * 4 + 0]);                                           \
      FMA4(a1, v1, W[q * 4 + 1]);                                           \
      FMA4(a2, v2, W[q * 4 + 2]);                                           \
      FMA4(a3, v3, W[q * 4 + 3]);                                           \
    }                                                                       \
    OUT = (bias) + ((a0 + a1) + (a2 + a3));                                 \
  }

// ---------------------------------------------------------------------------
// VALU-only 64-lane sum, zero LDS ops (round-6 proven).
// ---------------------------------------------------------------------------
__device__ __forceinline__ float wave_sum64(float v) {
  int x;
  x = __builtin_amdgcn_update_dpp(0, __float_as_int(v), 0x121, 0xF, 0xF, true);
  v += __int_as_float(x);  // row_ror:1
  x = __builtin_amdgcn_update_dpp(0, __float_as_int(v), 0x122, 0xF, 0xF, true);
  v += __int_as_float(x);  // row_ror:2
  x = __builtin_amdgcn_update_dpp(0, __float_as_int(v), 0x124, 0xF, 0xF, true);
  v += __int_as_float(x);  // row_ror:4
  x = __builtin_amdgcn_update_dpp(0, __float_as_int(v), 0x128, 0xF, 0xF, true);
  v += __int_as_float(x);  // row_ror:8
  x = __builtin_amdgcn_update_dpp(0, __float_as_int(v), 0x142, 0xF, 0xF, true);
  v += __int_as_float(x);  // row_bcast15
  x = __builtin_amdgcn_update_dpp(0, __float_as_int(v), 0x143, 0xF, 0xF, true);
  v += __int_as_float(x);  // row_bcast31: lanes48-63 = total
  return __int_as_float(__builtin_amdgcn_readlane(__float_as_int(v), 63));
}

#if defined(__has_builtin)
#if __has_builtin(__builtin_amdgcn_mfma_f32_16x16x32_f16)
#define HAVE_MFMA16 1
#endif
#endif

// ---------------------------------------------------------------------------
// Edge pass 1: ONE atomic yields both the degree histogram (final deg) and
// this edge's local slot (tmp_pos). fp16 weight pack rides along.
// (Replaces hist+scatter's duplicated 800K-atomic passes.)
// ---------------------------------------------------------------------------
__global__ __launch_bounds__(256) void edge_pass1_kernel(
    const int* __restrict__ dst, int* __restrict__ deg,
    int* __restrict__ tmp_pos, const float* __restrict__ Wl,
    const float* __restrict__ Wr, _Float16* __restrict__ w16, int E_) {
  int i = blockIdx.x * 256 + threadIdx.x;
  if (i < E_) tmp_pos[i] = atomicAdd(&deg[dst[i]], 1);
  if (i < 24576)
    w16[i] = (i < 12288) ? (_Float16)Wl[i] : (_Float16)Wr[i - 12288];
}

// ---------------------------------------------------------------------------
// scanA: per-256-segment local prefix + totals; FUSED degree histogram
// (128 bins, DESCENDING degree, LDS-aggregated).
// ---------------------------------------------------------------------------
__global__ __launch_bounds__(256) void scanA_kernel(
    const int* __restrict__ deg, int* __restrict__ row_ptr,
    int* __restrict__ segTot, int* __restrict__ bins, int N_, int nseg) {
  __shared__ int sb[256];
  __shared__ int lb[128];
  int t = threadIdx.x;
  if (t < 128) lb[t] = 0;
  __syncthreads();
  for (int s = blockIdx.x; s < nseg; s += gridDim.x) {
    int i = s * 256 + t;
    int v = (i < N_) ? deg[i] : 0;
    if (i < N_) atomicAdd(&lb[127 - min(v, 127)], 1);
    sb[t] = v;
    __syncthreads();
    for (int off = 1; off < 256; off <<= 1) {
      int a = (t >= off) ? sb[t - off] : 0;
      __syncthreads();
      sb[t] += a;
      __syncthreads();
    }
    int incl = sb[t];
    if (i < N_) row_ptr[i] = incl - v;
    if (t == 255) segTot[s] = incl;
    __syncthreads();
  }
  if (t < 128 && lb[t]) atomicAdd(&bins[t], lb[t]);
}

// ---------------------------------------------------------------------------
// scanB: scan segTot; FUSED exclusive scan of the 128 degree bins; FUSED
// graph counts via binary search over the SORTED batch array (removes the
// 50K same-address-contended float atomics entirely — G12).
// ---------------------------------------------------------------------------
__global__ __launch_bounds__(256) void scanB_kernel(
    int* __restrict__ segTot, int* __restrict__ bins,
    const int* __restrict__ batch, float* __restrict__ counts, int nseg,
    int N_, int G_) {
  __shared__ int sb[256];
  __shared__ int baseSh;
  int t = threadIdx.x;
  if (t == 0) baseSh = 0;
  __syncthreads();
  for (int c0 = 0; c0 < nseg; c0 += 256) {
    int s = c0 + t;
    int v = (s < nseg) ? segTot[s] : 0;
    sb[t] = v;
    __syncthreads();
    for (int off = 1; off < 256; off <<= 1) {
      int a = (t >= off) ? sb[t - off] : 0;
      __syncthreads();
      sb[t] += a;
      __syncthreads();
    }
    int incl = sb[t];
    int base = baseSh;
    if (s < nseg) segTot[s] = base + incl - v;
    __syncthreads();
    if (t == 255) baseSh = base + incl;
    __syncthreads();
  }
  int v2 = (t < 128) ? bins[t] : 0;
  sb[t] = v2;
  __syncthreads();
  for (int off = 1; off < 256; off <<= 1) {
    int a = (t >= off) ? sb[t - off] : 0;
    __syncthreads();
    sb[t] += a;
    __syncthreads();
  }
  if (t < 128) bins[t] = sb[t] - v2;
  // graph counts: counts[g] = lower_bound(g+1) - lower_bound(g)
  for (int g = t; g < G_; g += 256) {
    int lo = 0, hi = N_;
    while (lo < hi) {
      int mid = (lo + hi) >> 1;
      if (batch[mid] < g) lo = mid + 1; else hi = mid;
    }
    int lb0 = lo;
    hi = N_;
    while (lo < hi) {
      int mid = (lo + hi) >> 1;
      if (batch[mid] < g + 1) lo = mid + 1; else hi = mid;
    }
    counts[g] = (float)(lo - lb0);
  }
}

// ---------------------------------------------------------------------------
// scanC: finalize row_ptr; FUSED degree-sort scatter; zero csr pads.
// ---------------------------------------------------------------------------
__global__ __launch_bounds__(256) void scanC_kernel(
    int* __restrict__ row_ptr, const int* __restrict__ segTot,
    const int* __restrict__ deg, int* __restrict__ bins,
    int* __restrict__ perm, int* __restrict__ csr_src,
    int* __restrict__ csr_eid, int N_, int E_) {
  __shared__ int lb[128];
  __shared__ int lbase[128];
  int t = threadIdx.x;
  if (t < 128) lb[t] = 0;
  __syncthreads();
  int i = blockIdx.x * 256 + t;
  int bin = 0, rk = 0;
  bool ok = (i < N_);
  if (ok) {
    int rp = row_ptr[i] + segTot[i >> 8];
    row_ptr[i] = rp;
    int dg = deg[i];
    bin = 127 - min(dg, 127);
    rk = atomicAdd(&lb[bin], 1);
  }
  if (i == 0) row_ptr[N_] = E_;
  if (blockIdx.x == 0 && t < 16) {
    csr_src[E_ + t] = 0;
    csr_eid[E_ + t] = 0;
  }
  __syncthreads();
  if (t < 128) {
    int c = lb[t];
    lbase[t] = c ? atomicAdd(&bins[t], c) : 0;
  }
  __syncthreads();
  if (ok) perm[lbase[bin] + rk] = i;
}

// ---------------------------------------------------------------------------
// Edge pass 2: NO atomics — pos = row_ptr[dst] + tmp_pos. Coalesced reads
// (dst, src, tmp_pos), L2-cached random row_ptr reads, scattered 4B writes.
// ---------------------------------------------------------------------------
__global__ __launch_bounds__(256) void edge_pass2_kernel(
    const int* __restrict__ src, const int* __restrict__ dst,
    const int* __restrict__ row_ptr, const int* __restrict__ tmp_pos,
    int* __restrict__ csr_src, int* __restrict__ csr_eid, int E_) {
  int e = blockIdx.x * 256 + threadIdx.x;
  if (e >= E_) return;
  int pos = row_ptr[dst[e]] + tmp_pos[e];
  csr_src[pos] = src[e];
  csr_eid[pos] = e;
}

// ---------------------------------------------------------------------------
// Permute+convert attr: sequential coalesced 32B writes; random 64B-line
// gathers (each line read exactly once). (Split from scatter: round-5 proven
// — avoids scattered 32B attr writes / write amplification.)
// ---------------------------------------------------------------------------
__global__ __launch_bounds__(256) void permute_attr_kernel(
    const float4* __restrict__ edge_attr4, const int* __restrict__ csr_eid,
    unsigned* __restrict__ attr_u, int E_) {
  int p = blockIdx.x * 256 + threadIdx.x;
  if (p >= E_) return;
  int e = csr_eid[p];
  float4 a0 = edge_attr4[(size_t)e * 4 + 0];
  float4 a1 = edge_attr4[(size_t)e * 4 + 1];
  float4 a2 = edge_attr4[(size_t)e * 4 + 2];
  float4 a3 = edge_attr4[(size_t)e * 4 + 3];
  uint4 u0, u1;
  u0.x = pkh(a0.x, a0.y);
  u0.y = pkh(a0.z, a0.w);
  u0.z = pkh(a1.x, a1.y);
  u0.w = pkh(a1.z, a1.w);
  u1.x = pkh(a2.x, a2.y);
  u1.y = pkh(a2.z, a2.w);
  u1.z = pkh(a3.x, a3.y);
  u1.w = pkh(a3.z, a3.w);
  uint4* d4 = (uint4*)(attr_u + (size_t)p * 8);
  d4[0] = u0;
  d4[1] = u1;
}

// ---------------------------------------------------------------------------
// emb + FUSED layer-0 linx (round-11 proven).
// ---------------------------------------------------------------------------
__global__ __launch_bounds__(256, 3) void emb_kernel(
    const float* __restrict__ x, const float* __restrict__ emb_W,
    const float* __restrict__ emb_b, const _Float16* __restrict__ Wl16,
    const float* __restrict__ bl, const _Float16* __restrict__ Wr16,
    const float* __restrict__ br, float* __restrict__ h,
    _Float16* __restrict__ xl, _Float16* __restrict__ xr, int rows) {
  __shared__ float sx[4096];
  __shared__ float sh[64 * 68];
  int lane = threadIdx.x & 63;
  int w = threadIdx.x >> 6;
  int n0 = blockIdx.x * 64;

  {
    int gmax = rows * 64 - 4;
#pragma unroll
    for (int i = 0; i < 4; i++) {
      int off = w * 1024 + i * 256 + lane * 4;
      int g = min(n0 * 64 + off, gmax);
      *(float4*)(sx + off) = *(const float4*)(x + g);
    }
  }

  {
    float4 W[16];
#pragma unroll
    for (int q = 0; q < 16; q++) W[q] = ((const float4*)(emb_W + lane * 64))[q];
    float b = emb_b[lane];
#pragma unroll 1
    for (int t = 0; t < 16; t++) {
      int r = w * 16 + t;
      float a;
      DOT_ROW(sx, 64, r, b, a);
      sh[r * 68 + lane] = a;
      int n = n0 + r;
      if (n < rows) h[(size_t)n * 64 + lane] = a;
    }
  }

#ifdef HAVE_MFMA16
  {
    int r = lane & 15;
    int kg = lane >> 4;
    int nb = n0 + w * 16;
    const float* p = sh + (w * 16 + r) * 68 + kg * 8;
    f16x8 A0, A1;
    {
      float4 xa = *(const float4*)(p);
      float4 xb = *(const float4*)(p + 4);
      A0[0] = (_Float16)xa.x; A0[1] = (_Float16)xa.y;
      A0[2] = (_Float16)xa.z; A0[3] = (_Float16)xa.w;
      A0[4] = (_Float16)xb.x; A0[5] = (_Float16)xb.y;
      A0[6] = (_Float16)xb.z; A0[7] = (_Float16)xb.w;
      xa = *(const float4*)(p + 32);
      xb = *(const float4*)(p + 36);
      A1[0] = (_Float16)xa.x; A1[1] = (_Float16)xa.y;
      A1[2] = (_Float16)xa.z; A1[3] = (_Float16)xa.w;
      A1[4] = (_Float16)xb.x; A1[5] = (_Float16)xb.y;
      A1[6] = (_Float16)xb.z; A1[7] = (_Float16)xb.w;
    }
#pragma unroll
    for (int c = 0; c < 4; c++) {
      int o = c * 16 + r;
      {
        const f16x8* b0 = (const f16x8*)(Wl16 + (size_t)o * 64 + kg * 8);
        const f16x8* b1 = (const f16x8*)(Wl16 + (size_t)o * 64 + 32 + kg * 8);
        f32x4v acc;
        float bv = bl[o];
        acc[0] = bv; acc[1] = bv; acc[2] = bv; acc[3] = bv;
        acc = __builtin_amdgcn_mfma_f32_16x16x32_f16(A0, b0[0], acc, 0, 0, 0);
        acc = __builtin_amdgcn_mfma_f32_16x16x32_f16(A1, b1[0], acc, 0, 0, 0);
#pragma unroll
        for (int g = 0; g < 4; g++) {
          int nd = nb + kg * 4 + g;
          if (nd < rows) xl[(size_t)nd * 64 + o] = (_Float16)acc[g];
        }
      }
      {
        const f16x8* b0 = (const f16x8*)(Wr16 + (size_t)o * 64 + kg * 8);
        const f16x8* b1 = (const f16x8*)(Wr16 + (size_t)o * 64 + 32 + kg * 8);
        f32x4v acc;
        float bv = br[o];
        acc[0] = bv; acc[1] = bv; acc[2] = bv; acc[3] = bv;
        acc = __builtin_amdgcn_mfma_f32_16x16x32_f16(A0, b0[0], acc, 0, 0, 0);
        acc = __builtin_amdgcn_mfma_f32_16x16x32_f16(A1, b1[0], acc, 0, 0, 0);
#pragma unroll
        for (int g = 0; g < 4; g++) {
          int nd = nb + kg * 4 + g;
          if (nd < rows) xr[(size_t)nd * 64 + o] = (_Float16)acc[g];
        }
      }
    }
  }
#endif
}

// ---------------------------------------------------------------------------
// linx via MFMA (round-8 proven). Layers 1,2.
// ---------------------------------------------------------------------------
__global__ __launch_bounds__(256) void linx_mfma_kernel(
    const float* __restrict__ in, const _Float16* __restrict__ Wl16,
    const float* __restrict__ bl, const _Float16* __restrict__ Wr16,
    const float* __restrict__ br, _Float16* __restrict__ xl,
    _Float16* __restrict__ xr, int rows) {
#ifdef HAVE_MFMA16
  int lane = threadIdx.x & 63;
  int w = threadIdx.x >> 6;
  int n0 = blockIdx.x * 64 + w * 16;
  int r = lane & 15;
  int kg = lane >> 4;

  int nA = min(n0 + r, rows - 1);
  f16x8 A0, A1;
  {
    const float* p = in + (size_t)nA * 64 + kg * 8;
    float4 xa = *(const float4*)(p);
    float4 xb = *(const float4*)(p + 4);
    A0[0] = (_Float16)xa.x; A0[1] = (_Float16)xa.y;
    A0[2] = (_Float16)xa.z; A0[3] = (_Float16)xa.w;
    A0[4] = (_Float16)xb.x; A0[5] = (_Float16)xb.y;
    A0[6] = (_Float16)xb.z; A0[7] = (_Float16)xb.w;
    xa = *(const float4*)(p + 32);
    xb = *(const float4*)(p + 36);
    A1[0] = (_Float16)xa.x; A1[1] = (_Float16)xa.y;
    A1[2] = (_Float16)xa.z; A1[3] = (_Float16)xa.w;
    A1[4] = (_Float16)xb.x; A1[5] = (_Float16)xb.y;
    A1[6] = (_Float16)xb.z; A1[7] = (_Float16)xb.w;
  }

#pragma unroll
  for (int c = 0; c < 4; c++) {
    int o = c * 16 + r;
    {
      const f16x8* b0 = (const f16x8*)(Wl16 + (size_t)o * 64 + kg * 8);
      const f16x8* b1 = (const f16x8*)(Wl16 + (size_t)o * 64 + 32 + kg * 8);
      f32x4v acc;
      float bv = bl[o];
      acc[0] = bv; acc[1] = bv; acc[2] = bv; acc[3] = bv;
      acc = __builtin_amdgcn_mfma_f32_16x16x32_f16(A0, b0[0], acc, 0, 0, 0);
      acc = __builtin_amdgcn_mfma_f32_16x16x32_f16(A1, b1[0], acc, 0, 0, 0);
#pragma unroll
      for (int g = 0; g < 4; g++) {
        int nd = n0 + kg * 4 + g;
        if (nd < rows) xl[(size_t)nd * 64 + o] = (_Float16)acc[g];
      }
    }
    {
      const f16x8* b0 = (const f16x8*)(Wr16 + (size_t)o * 64 + kg * 8);
      const f16x8* b1 = (const f16x8*)(Wr16 + (size_t)o * 64 + 32 + kg * 8);
      f32x4v acc;
      float bv = br[o];
      acc[0] = bv; acc[1] = bv; acc[2] = bv; acc[3] = bv;
      acc = __builtin_amdgcn_mfma_f32_16x16x32_f16(A0, b0[0], acc, 0, 0, 0);
      acc = __builtin_amdgcn_mfma_f32_16x16x32_f16(A1, b1[0], acc, 0, 0, 0);
#pragma unroll
      for (int g = 0; g < 4; g++) {
        int nd = n0 + kg * 4 + g;
        if (nd < rows) xr[(size_t)nd * 64 + o] = (_Float16)acc[g];
      }
    }
  }
#endif
}

// ---------------------------------------------------------------------------
// Fused GATv2 layer (round-11/13 proven — best measured): one wave per
// (degree-sorted) node; 16/8/4-full + 4-padded chunks; scalar csr_src
// (readfirstlane -> SALU addressing); wave-uniform attr s_loads; fp16 xl
// gathers; ea via fdot2; LDS-free DPP reduction; online-max softmax via raw
// v_exp_f32 (exp2 domain). Epilogue = folded conv_bias+BN, exact GELU,
// residual.
// ---------------------------------------------------------------------------
template <bool CONTIG>
__global__ __launch_bounds__(256) void gat_fused_kernel(
    const int* __restrict__ perm, const int* __restrict__ csr_src,
    const int* __restrict__ csr_eid, const int* __restrict__ row_ptr,
    const unsigned* __restrict__ attr_u, const float* __restrict__ edge_attr,
    const _Float16* __restrict__ xl, const _Float16* __restrict__ xr,
    const float* __restrict__ We, const float* __restrict__ att,
    const float* __restrict__ conv_bias, const float* __restrict__ gamma,
    const float* __restrict__ beta, const float* __restrict__ mean,
    const float* __restrict__ var, float* __restrict__ h, int N_) {
  int widx = (blockIdx.x * 256 + threadIdx.x) >> 6;
  if (widx >= N_) return;
  int d = __builtin_amdgcn_readfirstlane(perm[widx]);
  int j = threadIdx.x & 63;
  half2v Wek2[8];
  float Wekf[16];
  if constexpr (CONTIG) {
#pragma unroll
    for (int q = 0; q < 8; q++) {
      Wek2[q][0] = (_Float16)We[j * 16 + 2 * q];
      Wek2[q][1] = (_Float16)We[j * 16 + 2 * q + 1];
    }
  } else {
#pragma unroll
    for (int k = 0; k < 16; k++) Wekf[k] = We[j * 16 + k];
  }
  float att_j = att[j] * ATT_SCALE;
  float sc = rsqrtf(var[j] + BN_EPS) * gamma[j];
  float sh = (conv_bias[j] - mean[j]) * sc + beta[j];

  int beg = __builtin_amdgcn_readfirstlane(row_ptr[d]);
  int end = __builtin_amdgcn_readfirstlane(row_ptr[d + 1]);
  float xrj = (float)xr[(size_t)d * 64 + j];
  float m = -INFINITY, l = 0.f, acc = 0.f;

  auto chunk = [&](int base, auto C_, auto PAD_) {
    constexpr int C = decltype(C_)::v;
    constexpr bool PAD = decltype(PAD_)::v;
    int si[C];
#pragma unroll
    for (int t = 0; t < C; t++) {
      int idx = PAD ? min(base + t, end - 1) : (base + t);
      si[t] = __builtin_amdgcn_readfirstlane(csr_src[idx]);  // SGPR -> SALU addr
    }
    float xlv[C];
#pragma unroll
    for (int t = 0; t < C; t++)
      xlv[t] = (float)xl[(size_t)si[t] * 64 + j];
    float v[C];
#pragma unroll
    for (int t = 0; t < C; t++) {
      int idx = PAD ? min(base + t, end - 1) : (base + t);
      float ea;
      if constexpr (CONTIG) {
        const uint4* ap = (const uint4*)(attr_u + (size_t)idx * 8);
        uint4 ua = ap[0], ub = ap[1];  // uniform -> s_load_dwordx4
        ea = 0.f;
        ea = FDOT2(u2h(ua.x), Wek2[0], ea);
        ea = FDOT2(u2h(ua.y), Wek2[1], ea);
        ea = FDOT2(u2h(ua.z), Wek2[2], ea);
        ea = FDOT2(u2h(ua.w), Wek2[3], ea);
        ea = FDOT2(u2h(ub.x), Wek2[4], ea);
        ea = FDOT2(u2h(ub.y), Wek2[5], ea);
        ea = FDOT2(u2h(ub.z), Wek2[6], ea);
        ea = FDOT2(u2h(ub.w), Wek2[7], ea);
      } else {
        const float4* ap =
            (const float4*)(edge_attr + (size_t)csr_eid[idx] * 16);
        float4 a0 = ap[0], a1 = ap[1], a2 = ap[2], a3 = ap[3];
        ea = a0.x * Wekf[0]  + a0.y * Wekf[1]  + a0.z * Wekf[2]  + a0.w * Wekf[3]
           + a1.x * Wekf[4]  + a1.y * Wekf[5]  + a1.z * Wekf[6]  + a1.w * Wekf[7]
           + a2.x * Wekf[8]  + a2.y * Wekf[9]  + a2.z * Wekf[10] + a2.w * Wekf[11]
           + a3.x * Wekf[12] + a3.y * Wekf[13] + a3.z * Wekf[14] + a3.w * Wekf[15];
      }
      float z = xlv[t] + xrj + ea;
      z = fmaxf(z, NEG_SLOPE * z);  // leaky_relu
      float p = wave_sum64(z * att_j);
      v[t] = (!PAD || (base + t < end)) ? p : -INFINITY;
    }
    float mc = v[0];
#pragma unroll
    for (int t = 1; t < C; t++) mc = fmaxf(mc, v[t]);
    float newm = fmaxf(m, mc);
    float s = FEXP(m - newm);  // first chunk: exp(-inf)=0
    l *= s;
    acc *= s;
#pragma unroll
    for (int t = 0; t < C; t++) {
      float w = FEXP(v[t] - newm);  // masked slots: exp(-inf)=0
      l += w;
      acc += w * xlv[t];
    }
    m = newm;
  };

  int base = beg;
  for (; base + 16 <= end; base += 16) chunk(base, IC<16>{}, BC<false>{});
  if (base + 8 <= end) {
    chunk(base, IC<8>{}, BC<false>{});
    base += 8;
  }
  if (base + 4 <= end) {
    chunk(base, IC<4>{}, BC<false>{});
    base += 4;
  }
  if (base < end) chunk(base, IC<4>{}, BC<true>{});

  float val = acc / (l + 1e-16f) * sc + sh;  // conv_bias+BN folded
  float g = 0.5f * val * (1.f + erff(val * 0.70710678118654752f));
  h[(size_t)d * 64 + j] += g;
}

// ---------------------------------------------------------------------------
// Final: out128 = h @ lin_W.T + lin_b, pooled per graph (round-4 proven).
// ---------------------------------------------------------------------------
__global__ __launch_bounds__(256, 2) void lin_pool_kernel(
    const float* __restrict__ h, const float* __restrict__ lin_W,
    const float* __restrict__ lin_b, const int* __restrict__ batch,
    const float* __restrict__ counts, float* __restrict__ pooled, int rows) {
  __shared__ float shh[4096];
  int lane = threadIdx.x & 63;
  int w = threadIdx.x >> 6;
  int n0 = blockIdx.x * 64;

  {
    int gmax = rows * 64 - 4;
#pragma unroll
    for (int i = 0; i < 4; i++) {
      int off = w * 1024 + i * 256 + lane * 4;
      int g = min(n0 * 64 + off, gmax);
      *(float4*)(shh + off) = *(const float4*)(h + g);
    }
  }

  float4 W0[16], W1[16];
#pragma unroll
  for (int q = 0; q < 16; q++) W0[q] = ((const float4*)(lin_W + lane * 64))[q];
#pragma unroll
  for (int q = 0; q < 16; q++)
    W1[q] = ((const float4*)(lin_W + (lane + 64) * 64))[q];
  float b0 = lin_b[lane], b1 = lin_b[lane + 64];

  int curg = -1;
  float acc0 = 0.f, acc1 = 0.f;
  int lim = min(16, rows - n0 - w * 16);
#pragma unroll 1
  for (int t = 0; t < lim; t++) {
    int r = w * 16 + t;
    __builtin_amdgcn_sched_barrier(0);
    float d0 = b0, d1 = b1;
#pragma unroll
    for (int q = 0; q < 16; q++) {
      float4 v = *(const float4*)(shh + r * 64 + q * 4);
      FMA4(d0, v, W0[q]);
      FMA4(d1, v, W1[q]);
    }
    int g = batch[n0 + r];
    if (g != curg) {
      if (curg >= 0) {
        float inv = 1.f / fmaxf(counts[curg], 1.f);
        atomicAdd(&pooled[curg * 128 + lane], acc0 * inv);
        atomicAdd(&pooled[curg * 128 + 64 + lane], acc1 * inv);
      }
      curg = g;
      acc0 = 0.f;
      acc1 = 0.f;
    }
    acc0 += d0;
    acc1 += d1;
  }
  if (curg >= 0) {
    float inv = 1.f / fmaxf(counts[curg], 1.f);
    atomicAdd(&pooled[curg * 128 + lane], acc0 * inv);
    atomicAdd(&pooled[curg * 128 + 64 + lane], acc1 * inv);
  }
}

extern "C" void kernel_launch(void* const* d_in, const int* in_sizes, int n_in,
                              void* d_out, int out_size, void* d_ws, size_t ws_size,
                              hipStream_t stream) {
  const float* x         = (const float*)d_in[0];
  const int*   edge_index= (const int*)  d_in[1];
  const float* edge_attr = (const float*)d_in[2];
  const int*   batch     = (const int*)  d_in[3];
  const float* emb_W     = (const float*)d_in[4];
  const float* emb_b     = (const float*)d_in[5];
  const float* Wl        = (const float*)d_in[6];
  const float* bl        = (const float*)d_in[7];
  const float* Wr        = (const float*)d_in[8];
  const float* br        = (const float*)d_in[9];
  const float* We        = (const float*)d_in[10];
  const float* att       = (const float*)d_in[11];
  const float* conv_bias = (const float*)d_in[12];
  const float* bn_gamma  = (const float*)d_in[13];
  const float* bn_beta   = (const float*)d_in[14];
  const float* bn_mean   = (const float*)d_in[15];
  const float* bn_var    = (const float*)d_in[16];
  const float* lin_W     = (const float*)d_in[17];
  const float* lin_b     = (const float*)d_in[18];

  const int N_ = in_sizes[0] / 64;
  const int E_ = in_sizes[1] / 2;
  const int G_ = out_size / 128;
  const int* src = edge_index;
  const int* dst = edge_index + E_;

  const int Npad = (N_ + 3) & ~3;
  const int Epad = (E_ + 19) & ~3;
  const int nseg = (N_ + 255) / 256;

  // Workspace layout (floats). xl/xr fp16. w16 = fp16 Wl(3)+Wr(3) packed.
  float* ws      = (float*)d_ws;
  float* h       = ws;                                 // N*64
  _Float16* xl   = (_Float16*)(h + (size_t)N_ * 64);   // N*64 halfs
  _Float16* xr   = xl + (size_t)N_ * 64;               // N*64 halfs
  int*   csr_src = (int*)(xr + (size_t)N_ * 64);       // Epad
  int*   csr_eid = csr_src + Epad;                     // Epad
  int*   row_ptr = csr_eid + Epad;                     // Npad+4
  int*   tmp_pos = row_ptr + (Npad + 4);               // Epad
  int*   deg     = tmp_pos + Epad;                     // Npad
  float* counts  = (float*)(deg + Npad);               // G
  int*   segTot  = (int*)(counts + G_);                // nseg+8
  int*   bins    = segTot + nseg + 8;                  // 128
  int*   perm    = bins + 128;                         // Npad
  uintptr_t abp  = (uintptr_t)(perm + Npad);
  abp = (abp + 15) & ~(uintptr_t)15;
  _Float16* w16  = (_Float16*)abp;                     // 24576 halfs (48KB)
  uintptr_t abp2 = abp + 24576 * sizeof(_Float16);
  unsigned* attr_u = (unsigned*)abp2;                  // E*8 uints (optional)

  size_t base_bytes = (abp2 - (uintptr_t)d_ws);
  bool contig = ws_size >= base_bytes + (size_t)E_ * 32 + 64;

  const int ngrid = (N_ + 255) / 256;
  const int egrid = (E_ + 255) / 256;

  // --- CSR build (single atomic pass) + degree-sort + weight pack ---
  // one memset zeroes deg + counts + segTot + bins (contiguous)
  hipMemsetAsync(deg, 0, ((size_t)Npad + G_ + nseg + 8 + 128) * 4, stream);
  edge_pass1_kernel<<<egrid, 256, 0, stream>>>(dst, deg, tmp_pos, Wl, Wr,
                                               w16, E_);
  scanA_kernel<<<min(nseg, 1024), 256, 0, stream>>>(deg, row_ptr, segTot,
                                                    bins, N_, nseg);
  scanB_kernel<<<1, 256, 0, stream>>>(segTot, bins, batch, counts, nseg, N_,
                                      G_);
  scanC_kernel<<<ngrid, 256, 0, stream>>>(row_ptr, segTot, deg, bins, perm,
                                          csr_src, csr_eid, N_, E_);
  edge_pass2_kernel<<<egrid, 256, 0, stream>>>(src, dst, row_ptr, tmp_pos,
                                               csr_src, csr_eid, E_);
  if (contig) {
    permute_attr_kernel<<<egrid, 256, 0, stream>>>(
        (const float4*)edge_attr, csr_eid, attr_u, E_);
  }

  // emb (fp32-exact) + fused layer-0 xl/xr (MFMA from LDS slab)
  const int tgrid = (N_ + 63) / 64;
  emb_kernel<<<tgrid, 256, 0, stream>>>(x, emb_W, emb_b, w16, bl,
                                        w16 + 12288, br, h, xl, xr, N_);

  const int gatBlocks = (N_ + 3) / 4;  // one wave per node
  for (int l = 0; l < 3; l++) {
    if (l > 0) {
      linx_mfma_kernel<<<tgrid, 256, 0, stream>>>(
          h, w16 + (size_t)l * 4096, bl + l * 64,
          w16 + 12288 + (size_t)l * 4096, br + l * 64, xl, xr, N_);
    }
    if (contig) {
      gat_fused_kernel<true><<<gatBlocks, 256, 0, stream>>>(
          perm, csr_src, csr_eid, row_ptr, attr_u, edge_attr, xl, xr,
          We + (size_t)l * 1024, att + l * 64, conv_bias + l * 64,
          bn_gamma + l * 64, bn_beta + l * 64, bn_mean + l * 64,
          bn_var + l * 64, h, N_);
    } else {
      gat_fused_kernel<false><<<gatBlocks, 256, 0, stream>>>(
          perm, csr_src, csr_eid, row_ptr, attr_u, edge_attr, xl, xr,
          We + (size_t)l * 1024, att + l * 64, conv_bias + l * 64,
          bn_gamma + l * 64, bn_beta + l * 64, bn_mean + l * 64,
          bn_var + l * 64, h, N_);
    }
  }

  hipMemsetAsync(d_out, 0, (size_t)G_ * 128 * 4, stream);
  lin_pool_kernel<<<(N_ + 63) / 64, 256, 0, stream>>>(
      h, lin_W, lin_b, batch, counts, (float*)d_out, N_);
}